// Round 6
// baseline (1485.564 us; speedup 1.0000x reference)
//
#include <hip/hip_runtime.h>
#include <cstdint>
#include <cstddef>

#define DF 64          // feature dim
#define NREL 8         // relations
#define DPB 128        // dst nodes per coarse bucket
#define DPB_SHIFT 7
#define NBMAX 1024     // max coarse buckets supported by LDS kernels
#define EPB 4096       // edges per binning block

typedef __attribute__((ext_vector_type(8))) short bf16x8;
typedef __attribute__((ext_vector_type(4))) float f32x4;

// ---- bf16 helpers (RNE) ---------------------------------------------------
static __device__ __forceinline__ unsigned short f2bf(float f) {
  unsigned int u = __float_as_uint(f);
  u += 0x7FFFu + ((u >> 16) & 1u);
  return (unsigned short)(u >> 16);
}
static __device__ __forceinline__ float bf2f(unsigned short s) {
  return __uint_as_float((unsigned int)s << 16);
}

// ---------------------------------------------------------------------------
// pack W (fp32 [64][64]) into bf16 MFMA B-fragments.
// frag[((mat*4 + nt)*2 + ks)*64 + l] = { W[ks*32 + (l>>4)*8 + j][nt*16 + (l&15)] }
// mats 0..7 = W1 relations, 8..15 = W2 relations.
// ---------------------------------------------------------------------------
__global__ __launch_bounds__(512) void pack_wfrag(
    const float* __restrict__ W1, const float* __restrict__ W2,
    bf16x8* __restrict__ frag)
{
  const int mat = blockIdx.x;    // 0..15
  const float* W = (mat < 8) ? (W1 + (size_t)mat * 4096)
                             : (W2 + (size_t)(mat - 8) * 4096);
  const int idx = threadIdx.x;   // 0..511
  const int nt = idx >> 7;
  const int ks = (idx >> 6) & 1;
  const int l  = idx & 63;
  const int col = nt * 16 + (l & 15);
  const int k0  = ks * 32 + (l >> 4) * 8;
  bf16x8 f;
#pragma unroll
  for (int j = 0; j < 8; ++j)
    f[j] = (short)f2bf(W[(size_t)(k0 + j) * 64 + col]);
  frag[(((size_t)mat * 4 + nt) * 2 + ks) * 64 + l] = f;
}

// ---------------------------------------------------------------------------
// MFMA transform: h[r][n][f] = sum_d xb[n][d] * W[r][d][f]  (bf16 in, bf16 out)
// block = 256 thr = 4 waves; block tile = 128 nodes; wave tile = 32 nodes x 64 f.
// ---------------------------------------------------------------------------
__global__ __launch_bounds__(256) void mfma_transform(
    const unsigned short* __restrict__ xb,   // [N][64] bf16
    const bf16x8* __restrict__ wfrag,        // [8][4][2][64]
    unsigned short* __restrict__ hb,         // [8][N][64] bf16
    int N)
{
  const int tid = threadIdx.x;
  const int l  = tid & 63;
  const int w  = tid >> 6;
  const int n0 = blockIdx.x * 128 + w * 32;
  const int lr = l & 15;   // A row / B col within 16-tile
  const int lg = l >> 4;   // k-group

  bf16x8 a[2][2];
#pragma unroll
  for (int mt = 0; mt < 2; ++mt) {
    const int row = n0 + mt * 16 + lr;
#pragma unroll
    for (int ks = 0; ks < 2; ++ks) {
      if (row < N)
        a[mt][ks] = *(const bf16x8*)&xb[(size_t)row * 64 + ks * 32 + lg * 8];
      else
        a[mt][ks] = (bf16x8)(short)0;
    }
  }

  for (int r = 0; r < NREL; ++r) {
    const bf16x8* wf = wfrag + (size_t)r * 8 * 64;
    bf16x8 b[4][2];
#pragma unroll
    for (int nt = 0; nt < 4; ++nt)
#pragma unroll
      for (int ks = 0; ks < 2; ++ks)
        b[nt][ks] = wf[(nt * 2 + ks) * 64 + l];

    f32x4 acc[2][4];
#pragma unroll
    for (int mt = 0; mt < 2; ++mt)
#pragma unroll
      for (int nt = 0; nt < 4; ++nt)
        acc[mt][nt] = (f32x4)(0.f);

#pragma unroll
    for (int ks = 0; ks < 2; ++ks)
#pragma unroll
      for (int mt = 0; mt < 2; ++mt)
#pragma unroll
        for (int nt = 0; nt < 4; ++nt)
          acc[mt][nt] = __builtin_amdgcn_mfma_f32_16x16x32_bf16(
              a[mt][ks], b[nt][ks], acc[mt][nt], 0, 0, 0);

    unsigned short* hr = hb + (size_t)r * N * 64;
#pragma unroll
    for (int mt = 0; mt < 2; ++mt) {
#pragma unroll
      for (int i = 0; i < 4; ++i) {
        const int node = n0 + mt * 16 + lg * 4 + i;
        if (node < N) {
          unsigned short* o = hr + (size_t)node * 64 + lr;
#pragma unroll
          for (int nt = 0; nt < 4; ++nt)
            o[nt * 16] = f2bf(acc[mt][nt][i]);
        }
      }
    }
  }
}

// ---------------------------------------------------------------------------
// fp32 vector transform (FALLBACK path only)
// ---------------------------------------------------------------------------
__global__ __launch_bounds__(128) void rgcn_transform(
    const float* __restrict__ x,
    const float* __restrict__ Wc,
    unsigned short* __restrict__ hb,
    int N)
{
  const int r = blockIdx.y;
  const float* W = Wc + (size_t)r * DF * DF;

  __shared__ float Ws[DF * DF];
  __shared__ float Xs[128 * 65];

  const int tid = threadIdx.x;
  const int n0 = blockIdx.x * 128;
  const int nrem = N - n0;

  {
    const float4* Wv = (const float4*)W;
    float4* Wsv = (float4*)Ws;
#pragma unroll
    for (int j = 0; j < 8; ++j) Wsv[tid + j * 128] = Wv[tid + j * 128];
  }
#pragma unroll
  for (int j = 0; j < 16; ++j) {
    int idx = tid + j * 128;
    int n = idx >> 4;
    int c4 = (idx & 15) * 4;
    float4 v = make_float4(0.f, 0.f, 0.f, 0.f);
    if (n < nrem) v = *(const float4*)&x[(size_t)(n0 + n) * DF + c4];
    float* p = &Xs[n * 65 + c4];
    p[0] = v.x; p[1] = v.y; p[2] = v.z; p[3] = v.w;
  }
  __syncthreads();

  const int fg = (tid & 7) * 8;
  const int ng = (tid >> 3) * 8;

  float4 a0[8], a1[8];
#pragma unroll
  for (int i = 0; i < 8; ++i) {
    a0[i] = make_float4(0.f, 0.f, 0.f, 0.f);
    a1[i] = make_float4(0.f, 0.f, 0.f, 0.f);
  }

#pragma unroll 4
  for (int d = 0; d < DF; ++d) {
    float4 w0 = *(const float4*)&Ws[d * DF + fg];
    float4 w1 = *(const float4*)&Ws[d * DF + fg + 4];
#pragma unroll
    for (int i = 0; i < 8; ++i) {
      float xv = Xs[(ng + i) * 65 + d];
      a0[i].x += xv * w0.x; a0[i].y += xv * w0.y;
      a0[i].z += xv * w0.z; a0[i].w += xv * w0.w;
      a1[i].x += xv * w1.x; a1[i].y += xv * w1.y;
      a1[i].z += xv * w1.z; a1[i].w += xv * w1.w;
    }
  }

#pragma unroll
  for (int i = 0; i < 8; ++i) {
    int n = ng + i;
    if (n < nrem) {
      uint4 pk;
      pk.x = (unsigned)f2bf(a0[i].x) | ((unsigned)f2bf(a0[i].y) << 16);
      pk.y = (unsigned)f2bf(a0[i].z) | ((unsigned)f2bf(a0[i].w) << 16);
      pk.z = (unsigned)f2bf(a1[i].x) | ((unsigned)f2bf(a1[i].y) << 16);
      pk.w = (unsigned)f2bf(a1[i].z) | ((unsigned)f2bf(a1[i].w) << 16);
      unsigned short* op = hb + (((size_t)r * N + (n0 + n)) << 6) + fg;
      *(uint4*)op = pk;
    }
  }
}

// ---------------------------------------------------------------------------
// epilogue (fp32): mode 0: out = x@root + b (overwrite)
//                  mode 1: out = relu(out + x@root + b)
//                  mode 2: out = out + x@root + b
// If xb != null, also emits xb = bf16(x) (input snapshot for MFMA transform).
// ---------------------------------------------------------------------------
__global__ __launch_bounds__(128) void rgcn_root_epilogue(
    const float* __restrict__ x,
    const float* __restrict__ root,
    const float* __restrict__ bias,
    float* __restrict__ out,
    unsigned short* __restrict__ xb,
    int N, int mode)
{
  __shared__ float Ws[DF * DF];
  __shared__ float Xs[128 * 65];

  const int tid = threadIdx.x;
  const int n0 = blockIdx.x * 128;
  const int nrem = N - n0;

  {
    const float4* Wv = (const float4*)root;
    float4* Wsv = (float4*)Ws;
#pragma unroll
    for (int j = 0; j < 8; ++j) Wsv[tid + j * 128] = Wv[tid + j * 128];
  }
#pragma unroll
  for (int j = 0; j < 16; ++j) {
    int idx = tid + j * 128;
    int n = idx >> 4;
    int c4 = (idx & 15) * 4;
    float4 v = make_float4(0.f, 0.f, 0.f, 0.f);
    if (n < nrem) {
      v = *(const float4*)&x[(size_t)(n0 + n) * DF + c4];
      if (xb) {
        uint2 pk;
        pk.x = (unsigned)f2bf(v.x) | ((unsigned)f2bf(v.y) << 16);
        pk.y = (unsigned)f2bf(v.z) | ((unsigned)f2bf(v.w) << 16);
        *(uint2*)&xb[(size_t)(n0 + n) * DF + c4] = pk;
      }
    }
    float* p = &Xs[n * 65 + c4];
    p[0] = v.x; p[1] = v.y; p[2] = v.z; p[3] = v.w;
  }
  __syncthreads();

  const int fg = (tid & 7) * 8;
  const int ng = (tid >> 3) * 8;

  float4 a0[8], a1[8];
#pragma unroll
  for (int i = 0; i < 8; ++i) {
    a0[i] = make_float4(0.f, 0.f, 0.f, 0.f);
    a1[i] = make_float4(0.f, 0.f, 0.f, 0.f);
  }

#pragma unroll 4
  for (int d = 0; d < DF; ++d) {
    float4 w0 = *(const float4*)&Ws[d * DF + fg];
    float4 w1 = *(const float4*)&Ws[d * DF + fg + 4];
#pragma unroll
    for (int i = 0; i < 8; ++i) {
      float xv = Xs[(ng + i) * 65 + d];
      a0[i].x += xv * w0.x; a0[i].y += xv * w0.y;
      a0[i].z += xv * w0.z; a0[i].w += xv * w0.w;
      a1[i].x += xv * w1.x; a1[i].y += xv * w1.y;
      a1[i].z += xv * w1.z; a1[i].w += xv * w1.w;
    }
  }

  float4 bb0 = *(const float4*)&bias[fg];
  float4 bb1 = *(const float4*)&bias[fg + 4];

#pragma unroll
  for (int i = 0; i < 8; ++i) {
    int n = ng + i;
    if (n < nrem) {
      float* op = out + (size_t)(n0 + n) * DF + fg;
      float4 o0, o1;
      if (mode == 0) {
        o0 = make_float4(a0[i].x + bb0.x, a0[i].y + bb0.y,
                         a0[i].z + bb0.z, a0[i].w + bb0.w);
        o1 = make_float4(a1[i].x + bb1.x, a1[i].y + bb1.y,
                         a1[i].z + bb1.z, a1[i].w + bb1.w);
      } else {
        o0 = *(float4*)op;
        o1 = *(float4*)(op + 4);
        o0.x += a0[i].x + bb0.x; o0.y += a0[i].y + bb0.y;
        o0.z += a0[i].z + bb0.z; o0.w += a0[i].w + bb0.w;
        o1.x += a1[i].x + bb1.x; o1.y += a1[i].y + bb1.y;
        o1.z += a1[i].z + bb1.z; o1.w += a1[i].w + bb1.w;
        if (mode == 1) {
          o0.x = fmaxf(o0.x, 0.f); o0.y = fmaxf(o0.y, 0.f);
          o0.z = fmaxf(o0.z, 0.f); o0.w = fmaxf(o0.w, 0.f);
          o1.x = fmaxf(o1.x, 0.f); o1.y = fmaxf(o1.y, 0.f);
          o1.z = fmaxf(o1.z, 0.f); o1.w = fmaxf(o1.w, 0.f);
        }
      }
      *(float4*)op = o0;
      *(float4*)(op + 4) = o1;
    }
  }
}

// ---------------------------------------------------------------------------
// CSR-lite build: zero -> bucket_count -> scan -> bin_scatter (u32 records)
// record: rel[3] << 24 | src[17] << 7 | local_dst[7]
// ---------------------------------------------------------------------------
__global__ __launch_bounds__(256) void zero_ints(int* __restrict__ p, int n)
{
  int i = blockIdx.x * 256 + threadIdx.x;
  if (i < n) p[i] = 0;
}

__global__ __launch_bounds__(256) void bucket_count(
    const int* __restrict__ dst, int* __restrict__ bcnt, int E, int NB)
{
  __shared__ int lh[NBMAX];
  const int t = threadIdx.x;
  for (int i = t; i < NB; i += 256) lh[i] = 0;
  __syncthreads();
  const int base = blockIdx.x * EPB;
  const int cnt = min(EPB, E - base);
  for (int k = t; k < cnt; k += 256)
    atomicAdd(&lh[dst[base + k] >> DPB_SHIFT], 1);
  __syncthreads();
  for (int i = t; i < NB; i += 256) {
    int c = lh[i];
    if (c) atomicAdd(&bcnt[i], c);
  }
}

__global__ __launch_bounds__(1024) void scan_buckets(
    const int* __restrict__ bcnt, int* __restrict__ boff,
    int* __restrict__ bcur, int NB, int E)
{
  __shared__ int sc[1024];
  const int t = threadIdx.x;
  int v = (t < NB) ? bcnt[t] : 0;
  sc[t] = v;
  __syncthreads();
  for (int off = 1; off < 1024; off <<= 1) {
    int u = (t >= off) ? sc[t - off] : 0;
    __syncthreads();
    sc[t] += u;
    __syncthreads();
  }
  if (t < NB) {
    int ex = sc[t] - v;
    boff[t] = ex;
    bcur[t] = ex;
  }
  if (t == 0) boff[NB] = E;
}

__global__ __launch_bounds__(256) void bin_scatter(
    const int* __restrict__ src, const int* __restrict__ dst,
    const int* __restrict__ et, int* __restrict__ bcur,
    unsigned int* __restrict__ binned, int E, int NB)
{
  __shared__ int lh[NBMAX];
  const int t = threadIdx.x;
  for (int i = t; i < NB; i += 256) lh[i] = 0;
  __syncthreads();
  const int base = blockIdx.x * EPB;
  const int cnt = min(EPB, E - base);
  for (int k = t; k < cnt; k += 256)
    atomicAdd(&lh[dst[base + k] >> DPB_SHIFT], 1);
  __syncthreads();
  for (int i = t; i < NB; i += 256) {
    int c = lh[i];
    lh[i] = c ? atomicAdd(&bcur[i], c) : 0;
  }
  __syncthreads();
  for (int k = t; k < cnt; k += 256) {
    int e = base + k;
    int d = dst[e];
    int pos = atomicAdd(&lh[d >> DPB_SHIFT], 1);
    binned[pos] = ((unsigned)et[e] << 24) | ((unsigned)src[e] << 7) |
                  ((unsigned)d & (DPB - 1));
  }
}

// ---------------------------------------------------------------------------
// bucket_gather: one block per 128-dst bucket; LDS fp32 accumulator.
// Sequential coalesced read of binned records; 8 lanes/edge read 16B of the
// h row and atomicAdd into LDS; then out[node] = (out[node] + acc) (+relu).
// ---------------------------------------------------------------------------
static __device__ __forceinline__ void acc8(
    float* __restrict__ acc, unsigned w, int l8, const uint4& u)
{
  float* a = &acc[(int)(w & (DPB - 1)) * DF + l8];
  atomicAdd(a + 0, bf2f((unsigned short)u.x));
  atomicAdd(a + 1, bf2f((unsigned short)(u.x >> 16)));
  atomicAdd(a + 2, bf2f((unsigned short)u.y));
  atomicAdd(a + 3, bf2f((unsigned short)(u.y >> 16)));
  atomicAdd(a + 4, bf2f((unsigned short)u.z));
  atomicAdd(a + 5, bf2f((unsigned short)(u.z >> 16)));
  atomicAdd(a + 6, bf2f((unsigned short)u.w));
  atomicAdd(a + 7, bf2f((unsigned short)(u.w >> 16)));
}

__global__ __launch_bounds__(512) void bucket_gather(
    const unsigned int* __restrict__ binned,
    const int* __restrict__ boff,
    const unsigned short* __restrict__ hb,   // [8][N][64] bf16
    float* __restrict__ out,                 // [N][64] fp32 (has x@root+b)
    int N, int do_relu)
{
  __shared__ float acc[DPB * DF];            // 32 KB
  const int t = threadIdx.x;
  const int b = blockIdx.x;

  float4* av = (float4*)acc;
#pragma unroll
  for (int i = 0; i < (DPB * DF / 4) / 512; ++i)
    av[t + i * 512] = make_float4(0.f, 0.f, 0.f, 0.f);
  __syncthreads();

  const int beg = boff[b], end = boff[b + 1];
  const int l8 = (t & 7) * 8;     // bf16 feature offset
  const int eg = t >> 3;          // 0..63 edge slot
  int p = beg + eg;

  // 4x unrolled: 256 edges per step, 4 independent loads in flight
  for (; p + 192 < end; p += 256) {
    unsigned w0 = binned[p];
    unsigned w1 = binned[p + 64];
    unsigned w2 = binned[p + 128];
    unsigned w3 = binned[p + 192];
    uint4 u0 = *(const uint4*)&hb[(((size_t)(w0 >> 24) * N + ((w0 >> 7) & 0x1FFFFu)) << 6) + l8];
    uint4 u1 = *(const uint4*)&hb[(((size_t)(w1 >> 24) * N + ((w1 >> 7) & 0x1FFFFu)) << 6) + l8];
    uint4 u2 = *(const uint4*)&hb[(((size_t)(w2 >> 24) * N + ((w2 >> 7) & 0x1FFFFu)) << 6) + l8];
    uint4 u3 = *(const uint4*)&hb[(((size_t)(w3 >> 24) * N + ((w3 >> 7) & 0x1FFFFu)) << 6) + l8];
    acc8(acc, w0, l8, u0);
    acc8(acc, w1, l8, u1);
    acc8(acc, w2, l8, u2);
    acc8(acc, w3, l8, u3);
  }
  for (; p < end; p += 64) {
    unsigned w0 = binned[p];
    uint4 u0 = *(const uint4*)&hb[(((size_t)(w0 >> 24) * N + ((w0 >> 7) & 0x1FFFFu)) << 6) + l8];
    acc8(acc, w0, l8, u0);
  }
  __syncthreads();

  // merge: 16 threads per node, 32 nodes per iter, 4 iters
  const int dbase = b << DPB_SHIFT;
  const int f4 = (t & 15) * 4;
#pragma unroll
  for (int it = 0; it < 4; ++it) {
    const int nl = (t >> 4) + it * 32;
    const int node = dbase + nl;
    if (node < N) {
      float* o = out + ((size_t)node << 6) + f4;
      float4 cv = *(float4*)o;
      float4 a = *(float4*)&acc[nl * DF + f4];
      cv.x += a.x; cv.y += a.y; cv.z += a.z; cv.w += a.w;
      if (do_relu) {
        cv.x = fmaxf(cv.x, 0.f); cv.y = fmaxf(cv.y, 0.f);
        cv.z = fmaxf(cv.z, 0.f); cv.w = fmaxf(cv.w, 0.f);
      }
      *(float4*)o = cv;
    }
  }
}

// ---------------------------------------------------------------------------
// fallback atomic scatter (bf16 h) — only if ws too small for CSR path
// ---------------------------------------------------------------------------
__global__ __launch_bounds__(256) void rgcn_scatter(
    const int* __restrict__ src, const int* __restrict__ dst,
    const int* __restrict__ et,
    const unsigned short* __restrict__ hb,
    float* __restrict__ out,
    int E, int N, int r0, int r1)
{
  long long g = (long long)blockIdx.x * 256 + threadIdx.x;
  int e = (int)(g >> 4);
  if (e >= E) return;
  int r = et[e];
  if (r < r0 || r >= r1) return;
  int f4 = ((int)g & 15) * 4;
  int s = src[e];
  int d = dst[e];
  ushort4 u = *(const ushort4*)&hb[(((size_t)(r - r0) * N + s) << 6) + f4];
  float* o = out + ((size_t)d << 6) + f4;
  atomicAdd(o + 0, bf2f(u.x));
  atomicAdd(o + 1, bf2f(u.y));
  atomicAdd(o + 2, bf2f(u.z));
  atomicAdd(o + 3, bf2f(u.w));
}

// ---------------------------------------------------------------------------
extern "C" void kernel_launch(void* const* d_in, const int* in_sizes, int n_in,
                              void* d_out, int out_size, void* d_ws, size_t ws_size,
                              hipStream_t stream) {
  const int* adj    = (const int*)d_in[0];    // [2, E]
  const float* feat = (const float*)d_in[1];  // [N, 64]
  const int* et     = (const int*)d_in[2];    // [E]
  const float* W1   = (const float*)d_in[3];
  const float* rt1  = (const float*)d_in[4];
  const float* b1   = (const float*)d_in[5];
  const float* W2   = (const float*)d_in[6];
  const float* rt2  = (const float*)d_in[7];
  const float* b2   = (const float*)d_in[8];

  const int E = in_sizes[0] / 2;
  const int N = in_sizes[1] / DF;
  const int* srcp = adj;
  const int* dstp = adj + E;

  float* out = (float*)d_out;
  const size_t ND = (size_t)N * DF;
  const int nblk = (N + 127) / 128;
  const int NB = (N + DPB - 1) >> DPB_SHIFT;

  // ws layout: hb bf16[8,N,64] | xb bf16[N,64] | wfrag | binned u32[E] |
  //            bcnt[NB] | boff[NB+1] | bcur[NB]
  const size_t wfrag_elems = (size_t)16 * 8 * 64;  // bf16x8 units
  const size_t need_csr = 8 * ND * 2 + ND * 2 + wfrag_elems * 16 +
                          (size_t)E * 4 + ((size_t)3 * NB + 1) * 4;

  if (ws_size >= need_csr && NB <= NBMAX && N < (1 << 17)) {
    unsigned short* hb = (unsigned short*)d_ws;
    unsigned short* xb = hb + 8 * ND;
    bf16x8* wfrag = (bf16x8*)(xb + ND);
    unsigned int* binned = (unsigned int*)(wfrag + wfrag_elems);
    int* bcnt = (int*)(binned + E);
    int* boff = bcnt + NB;
    int* bcur = boff + (NB + 1);

    // ---- build bucket-grouped edge list once (same graph both layers) ----
    const int ebk = (E + EPB - 1) / EPB;
    zero_ints<<<(NB + 255) / 256, 256, 0, stream>>>(bcnt, NB);
    bucket_count<<<ebk, 256, 0, stream>>>(dstp, bcnt, E, NB);
    scan_buckets<<<1, 1024, 0, stream>>>(bcnt, boff, bcur, NB, E);
    bin_scatter<<<ebk, 256, 0, stream>>>(srcp, dstp, et, bcur, binned, E, NB);

    // ---- pack weights into MFMA fragments (both layers) ----
    pack_wfrag<<<16, 512, 0, stream>>>(W1, W2, wfrag);

    // ---- layer 1: out = relu( agg(h1) + feat@rt1 + b1 ) ----
    rgcn_root_epilogue<<<nblk, 128, 0, stream>>>(feat, rt1, b1, out, xb, N, 0);
    mfma_transform<<<nblk, 256, 0, stream>>>(xb, wfrag, hb, N);
    bucket_gather<<<NB, 512, 0, stream>>>(binned, boff, hb, out, N, 1);

    // ---- layer 2: out = agg(h2) + out@rt2 + b2 ----
    rgcn_root_epilogue<<<nblk, 128, 0, stream>>>(out, rt2, b2, out, xb, N, 0);
    mfma_transform<<<nblk, 256, 0, stream>>>(xb, wfrag + (size_t)8 * 8 * 64, hb, N);
    bucket_gather<<<NB, 512, 0, stream>>>(binned, boff, hb, out, N, 0);
    return;
  }

  // ---------------- fallback: atomic scatter ----------------
  size_t per_rel = ND * sizeof(unsigned short);
  size_t xmid_b = ND * sizeof(float);
  int RC = 1;
  if (ws_size > per_rel + xmid_b) {
    size_t rc = (ws_size - xmid_b) / per_rel;
    RC = rc >= NREL ? NREL : (int)rc;
  }
  unsigned short* hb = (unsigned short*)d_ws;
  float* xmid = (float*)((char*)d_ws + (size_t)RC * per_rel);
  const int sblk = (int)(((size_t)E * 16 + 255) / 256);

  for (int layer = 0; layer < 2; ++layer) {
    const float* xin = layer ? xmid : feat;
    const float* W   = layer ? W2 : W1;
    const float* rt  = layer ? rt2 : rt1;
    const float* bs  = layer ? b2 : b1;
    float* o         = layer ? out : xmid;

    hipMemsetAsync(o, 0, ND * sizeof(float), stream);
    for (int r0 = 0; r0 < NREL; r0 += RC) {
      int rc = (NREL - r0) < RC ? (NREL - r0) : RC;
      rgcn_transform<<<dim3(nblk, rc), 128, 0, stream>>>(
          xin, W + (size_t)r0 * DF * DF, hb, N);
      rgcn_scatter<<<sblk, 256, 0, stream>>>(
          srcp, dstp, et, hb, o, E, N, r0, r0 + rc);
    }
    rgcn_root_epilogue<<<nblk, 128, 0, stream>>>(xin, rt, bs, o, nullptr, N,
                                                 layer == 0 ? 1 : 2);
  }
}

// Round 7
// 219.835 us; speedup vs baseline: 6.7576x; 6.7576x over previous
//
#include <hip/hip_runtime.h>
#include <cstdint>
#include <cstddef>

#define DF 64          // feature dim
#define NREL 8         // relations
#define DPB 128        // dst nodes per coarse bucket
#define DPB_SHIFT 7
#define NBMAX 1024     // max coarse buckets supported by LDS kernels
#define EPB 4096       // edges per binning block

typedef __attribute__((ext_vector_type(8))) short bf16x8;
typedef __attribute__((ext_vector_type(4))) float f32x4;

// ---- bf16 helpers (RNE) ---------------------------------------------------
static __device__ __forceinline__ unsigned short f2bf(float f) {
  unsigned int u = __float_as_uint(f);
  u += 0x7FFFu + ((u >> 16) & 1u);
  return (unsigned short)(u >> 16);
}
static __device__ __forceinline__ float bf2f(unsigned short s) {
  return __uint_as_float((unsigned int)s << 16);
}

// ---------------------------------------------------------------------------
// pack W (fp32 [64][64]) into bf16 MFMA B-fragments.
// frag[((mat*4 + nt)*2 + ks)*64 + l] = { W[ks*32 + (l>>4)*8 + j][nt*16 + (l&15)] }
// mats 0..7 = W1 relations, 8..15 = W2 relations.
// ---------------------------------------------------------------------------
__global__ __launch_bounds__(512) void pack_wfrag(
    const float* __restrict__ W1, const float* __restrict__ W2,
    bf16x8* __restrict__ frag)
{
  const int mat = blockIdx.x;    // 0..15
  const float* W = (mat < 8) ? (W1 + (size_t)mat * 4096)
                             : (W2 + (size_t)(mat - 8) * 4096);
  const int idx = threadIdx.x;   // 0..511
  const int nt = idx >> 7;
  const int ks = (idx >> 6) & 1;
  const int l  = idx & 63;
  const int col = nt * 16 + (l & 15);
  const int k0  = ks * 32 + (l >> 4) * 8;
  bf16x8 f;
#pragma unroll
  for (int j = 0; j < 8; ++j)
    f[j] = (short)f2bf(W[(size_t)(k0 + j) * 64 + col]);
  frag[(((size_t)mat * 4 + nt) * 2 + ks) * 64 + l] = f;
}

// ---------------------------------------------------------------------------
// MFMA transform: h[r][n][f] = sum_d xb[n][d] * W[r][d][f]  (bf16 in, bf16 out)
// block = 256 thr = 4 waves; block tile = 128 nodes; wave tile = 32 nodes x 64 f.
// ---------------------------------------------------------------------------
__global__ __launch_bounds__(256) void mfma_transform(
    const unsigned short* __restrict__ xb,   // [N][64] bf16
    const bf16x8* __restrict__ wfrag,        // [8][4][2][64]
    unsigned short* __restrict__ hb,         // [8][N][64] bf16
    int N)
{
  const int tid = threadIdx.x;
  const int l  = tid & 63;
  const int w  = tid >> 6;
  const int n0 = blockIdx.x * 128 + w * 32;
  const int lr = l & 15;   // A row / B col within 16-tile
  const int lg = l >> 4;   // k-group

  bf16x8 a[2][2];
#pragma unroll
  for (int mt = 0; mt < 2; ++mt) {
    const int row = n0 + mt * 16 + lr;
#pragma unroll
    for (int ks = 0; ks < 2; ++ks) {
      if (row < N)
        a[mt][ks] = *(const bf16x8*)&xb[(size_t)row * 64 + ks * 32 + lg * 8];
      else
        a[mt][ks] = (bf16x8)(short)0;
    }
  }

  for (int r = 0; r < NREL; ++r) {
    const bf16x8* wf = wfrag + (size_t)r * 8 * 64;
    bf16x8 b[4][2];
#pragma unroll
    for (int nt = 0; nt < 4; ++nt)
#pragma unroll
      for (int ks = 0; ks < 2; ++ks)
        b[nt][ks] = wf[(nt * 2 + ks) * 64 + l];

    f32x4 acc[2][4];
#pragma unroll
    for (int mt = 0; mt < 2; ++mt)
#pragma unroll
      for (int nt = 0; nt < 4; ++nt)
        acc[mt][nt] = (f32x4)(0.f);

#pragma unroll
    for (int ks = 0; ks < 2; ++ks)
#pragma unroll
      for (int mt = 0; mt < 2; ++mt)
#pragma unroll
        for (int nt = 0; nt < 4; ++nt)
          acc[mt][nt] = __builtin_amdgcn_mfma_f32_16x16x32_bf16(
              a[mt][ks], b[nt][ks], acc[mt][nt], 0, 0, 0);

    unsigned short* hr = hb + (size_t)r * N * 64;
#pragma unroll
    for (int mt = 0; mt < 2; ++mt) {
#pragma unroll
      for (int i = 0; i < 4; ++i) {
        const int node = n0 + mt * 16 + lg * 4 + i;
        if (node < N) {
          unsigned short* o = hr + (size_t)node * 64 + lr;
#pragma unroll
          for (int nt = 0; nt < 4; ++nt)
            o[nt * 16] = f2bf(acc[mt][nt][i]);
        }
      }
    }
  }
}

// ---------------------------------------------------------------------------
// fp32 vector transform (FALLBACK path only)
// ---------------------------------------------------------------------------
__global__ __launch_bounds__(128) void rgcn_transform(
    const float* __restrict__ x,
    const float* __restrict__ Wc,
    unsigned short* __restrict__ hb,
    int N)
{
  const int r = blockIdx.y;
  const float* W = Wc + (size_t)r * DF * DF;

  __shared__ float Ws[DF * DF];
  __shared__ float Xs[128 * 65];

  const int tid = threadIdx.x;
  const int n0 = blockIdx.x * 128;
  const int nrem = N - n0;

  {
    const float4* Wv = (const float4*)W;
    float4* Wsv = (float4*)Ws;
#pragma unroll
    for (int j = 0; j < 8; ++j) Wsv[tid + j * 128] = Wv[tid + j * 128];
  }
#pragma unroll
  for (int j = 0; j < 16; ++j) {
    int idx = tid + j * 128;
    int n = idx >> 4;
    int c4 = (idx & 15) * 4;
    float4 v = make_float4(0.f, 0.f, 0.f, 0.f);
    if (n < nrem) v = *(const float4*)&x[(size_t)(n0 + n) * DF + c4];
    float* p = &Xs[n * 65 + c4];
    p[0] = v.x; p[1] = v.y; p[2] = v.z; p[3] = v.w;
  }
  __syncthreads();

  const int fg = (tid & 7) * 8;
  const int ng = (tid >> 3) * 8;

  float4 a0[8], a1[8];
#pragma unroll
  for (int i = 0; i < 8; ++i) {
    a0[i] = make_float4(0.f, 0.f, 0.f, 0.f);
    a1[i] = make_float4(0.f, 0.f, 0.f, 0.f);
  }

#pragma unroll 4
  for (int d = 0; d < DF; ++d) {
    float4 w0 = *(const float4*)&Ws[d * DF + fg];
    float4 w1 = *(const float4*)&Ws[d * DF + fg + 4];
#pragma unroll
    for (int i = 0; i < 8; ++i) {
      float xv = Xs[(ng + i) * 65 + d];
      a0[i].x += xv * w0.x; a0[i].y += xv * w0.y;
      a0[i].z += xv * w0.z; a0[i].w += xv * w0.w;
      a1[i].x += xv * w1.x; a1[i].y += xv * w1.y;
      a1[i].z += xv * w1.z; a1[i].w += xv * w1.w;
    }
  }

#pragma unroll
  for (int i = 0; i < 8; ++i) {
    int n = ng + i;
    if (n < nrem) {
      uint4 pk;
      pk.x = (unsigned)f2bf(a0[i].x) | ((unsigned)f2bf(a0[i].y) << 16);
      pk.y = (unsigned)f2bf(a0[i].z) | ((unsigned)f2bf(a0[i].w) << 16);
      pk.z = (unsigned)f2bf(a1[i].x) | ((unsigned)f2bf(a1[i].y) << 16);
      pk.w = (unsigned)f2bf(a1[i].z) | ((unsigned)f2bf(a1[i].w) << 16);
      unsigned short* op = hb + (((size_t)r * N + (n0 + n)) << 6) + fg;
      *(uint4*)op = pk;
    }
  }
}

// ---------------------------------------------------------------------------
// epilogue (fp32): mode 0: out = x@root + b (overwrite)
//                  mode 1: out = relu(out + x@root + b)
//                  mode 2: out = out + x@root + b
// If xb != null, also emits xb = bf16(x) (input snapshot for MFMA transform).
// ---------------------------------------------------------------------------
__global__ __launch_bounds__(128) void rgcn_root_epilogue(
    const float* __restrict__ x,
    const float* __restrict__ root,
    const float* __restrict__ bias,
    float* __restrict__ out,
    unsigned short* __restrict__ xb,
    int N, int mode)
{
  __shared__ float Ws[DF * DF];
  __shared__ float Xs[128 * 65];

  const int tid = threadIdx.x;
  const int n0 = blockIdx.x * 128;
  const int nrem = N - n0;

  {
    const float4* Wv = (const float4*)root;
    float4* Wsv = (float4*)Ws;
#pragma unroll
    for (int j = 0; j < 8; ++j) Wsv[tid + j * 128] = Wv[tid + j * 128];
  }
#pragma unroll
  for (int j = 0; j < 16; ++j) {
    int idx = tid + j * 128;
    int n = idx >> 4;
    int c4 = (idx & 15) * 4;
    float4 v = make_float4(0.f, 0.f, 0.f, 0.f);
    if (n < nrem) {
      v = *(const float4*)&x[(size_t)(n0 + n) * DF + c4];
      if (xb) {
        uint2 pk;
        pk.x = (unsigned)f2bf(v.x) | ((unsigned)f2bf(v.y) << 16);
        pk.y = (unsigned)f2bf(v.z) | ((unsigned)f2bf(v.w) << 16);
        *(uint2*)&xb[(size_t)(n0 + n) * DF + c4] = pk;
      }
    }
    float* p = &Xs[n * 65 + c4];
    p[0] = v.x; p[1] = v.y; p[2] = v.z; p[3] = v.w;
  }
  __syncthreads();

  const int fg = (tid & 7) * 8;
  const int ng = (tid >> 3) * 8;

  float4 a0[8], a1[8];
#pragma unroll
  for (int i = 0; i < 8; ++i) {
    a0[i] = make_float4(0.f, 0.f, 0.f, 0.f);
    a1[i] = make_float4(0.f, 0.f, 0.f, 0.f);
  }

#pragma unroll 4
  for (int d = 0; d < DF; ++d) {
    float4 w0 = *(const float4*)&Ws[d * DF + fg];
    float4 w1 = *(const float4*)&Ws[d * DF + fg + 4];
#pragma unroll
    for (int i = 0; i < 8; ++i) {
      float xv = Xs[(ng + i) * 65 + d];
      a0[i].x += xv * w0.x; a0[i].y += xv * w0.y;
      a0[i].z += xv * w0.z; a0[i].w += xv * w0.w;
      a1[i].x += xv * w1.x; a1[i].y += xv * w1.y;
      a1[i].z += xv * w1.z; a1[i].w += xv * w1.w;
    }
  }

  float4 bb0 = *(const float4*)&bias[fg];
  float4 bb1 = *(const float4*)&bias[fg + 4];

#pragma unroll
  for (int i = 0; i < 8; ++i) {
    int n = ng + i;
    if (n < nrem) {
      float* op = out + (size_t)(n0 + n) * DF + fg;
      float4 o0, o1;
      if (mode == 0) {
        o0 = make_float4(a0[i].x + bb0.x, a0[i].y + bb0.y,
                         a0[i].z + bb0.z, a0[i].w + bb0.w);
        o1 = make_float4(a1[i].x + bb1.x, a1[i].y + bb1.y,
                         a1[i].z + bb1.z, a1[i].w + bb1.w);
      } else {
        o0 = *(float4*)op;
        o1 = *(float4*)(op + 4);
        o0.x += a0[i].x + bb0.x; o0.y += a0[i].y + bb0.y;
        o0.z += a0[i].z + bb0.z; o0.w += a0[i].w + bb0.w;
        o1.x += a1[i].x + bb1.x; o1.y += a1[i].y + bb1.y;
        o1.z += a1[i].z + bb1.z; o1.w += a1[i].w + bb1.w;
        if (mode == 1) {
          o0.x = fmaxf(o0.x, 0.f); o0.y = fmaxf(o0.y, 0.f);
          o0.z = fmaxf(o0.z, 0.f); o0.w = fmaxf(o0.w, 0.f);
          o1.x = fmaxf(o1.x, 0.f); o1.y = fmaxf(o1.y, 0.f);
          o1.z = fmaxf(o1.z, 0.f); o1.w = fmaxf(o1.w, 0.f);
        }
      }
      *(float4*)op = o0;
      *(float4*)(op + 4) = o1;
    }
  }
}

// ---------------------------------------------------------------------------
// CSR build: zero -> bucket_count -> scan -> bin_scatter -> fill_bucket
// record (u32): rel[3] << 24 | src[17] << 7 | local_dst[7]
// ---------------------------------------------------------------------------
__global__ __launch_bounds__(256) void zero_ints(int* __restrict__ p, int n)
{
  int i = blockIdx.x * 256 + threadIdx.x;
  if (i < n) p[i] = 0;
}

__global__ __launch_bounds__(256) void bucket_count(
    const int* __restrict__ dst, int* __restrict__ bcnt, int E, int NB)
{
  __shared__ int lh[NBMAX];
  const int t = threadIdx.x;
  for (int i = t; i < NB; i += 256) lh[i] = 0;
  __syncthreads();
  const int base = blockIdx.x * EPB;
  const int cnt = min(EPB, E - base);
  for (int k = t; k < cnt; k += 256)
    atomicAdd(&lh[dst[base + k] >> DPB_SHIFT], 1);
  __syncthreads();
  for (int i = t; i < NB; i += 256) {
    int c = lh[i];
    if (c) atomicAdd(&bcnt[i], c);
  }
}

__global__ __launch_bounds__(1024) void scan_buckets(
    const int* __restrict__ bcnt, int* __restrict__ boff,
    int* __restrict__ bcur, int NB, int E)
{
  __shared__ int sc[1024];
  const int t = threadIdx.x;
  int v = (t < NB) ? bcnt[t] : 0;
  sc[t] = v;
  __syncthreads();
  for (int off = 1; off < 1024; off <<= 1) {
    int u = (t >= off) ? sc[t - off] : 0;
    __syncthreads();
    sc[t] += u;
    __syncthreads();
  }
  if (t < NB) {
    int ex = sc[t] - v;
    boff[t] = ex;
    bcur[t] = ex;
  }
  if (t == 0) boff[NB] = E;
}

__global__ __launch_bounds__(256) void bin_scatter(
    const int* __restrict__ src, const int* __restrict__ dst,
    const int* __restrict__ et, int* __restrict__ bcur,
    unsigned int* __restrict__ binned, int E, int NB)
{
  __shared__ int lh[NBMAX];
  const int t = threadIdx.x;
  for (int i = t; i < NB; i += 256) lh[i] = 0;
  __syncthreads();
  const int base = blockIdx.x * EPB;
  const int cnt = min(EPB, E - base);
  for (int k = t; k < cnt; k += 256)
    atomicAdd(&lh[dst[base + k] >> DPB_SHIFT], 1);
  __syncthreads();
  for (int i = t; i < NB; i += 256) {
    int c = lh[i];
    lh[i] = c ? atomicAdd(&bcur[i], c) : 0;
  }
  __syncthreads();
  for (int k = t; k < cnt; k += 256) {
    int e = base + k;
    int d = dst[e];
    int pos = atomicAdd(&lh[d >> DPB_SHIFT], 1);
    binned[pos] = ((unsigned)et[e] << 24) | ((unsigned)src[e] << 7) |
                  ((unsigned)d & (DPB - 1));
  }
}

// per-bucket local count/scan/scatter -> row_ptr + per-node-grouped records
__global__ __launch_bounds__(256) void fill_bucket(
    const unsigned int* __restrict__ binned, const int* __restrict__ boff,
    int* __restrict__ row_ptr, unsigned int* __restrict__ sorted,
    int N, int E)
{
  __shared__ int h[DPB];
  __shared__ int sc[DPB];
  __shared__ int cur[DPB];
  const int t = threadIdx.x;
  const int b = blockIdx.x;
  const int beg = boff[b], end = boff[b + 1];
  const int dbase = b << DPB_SHIFT;

  if (t < DPB) h[t] = 0;
  __syncthreads();
  for (int k = beg + t; k < end; k += 256)
    atomicAdd(&h[binned[k] & (DPB - 1)], 1);
  __syncthreads();
  if (t < DPB) sc[t] = h[t];
  __syncthreads();
  for (int off = 1; off < DPB; off <<= 1) {
    int u = (t < DPB && t >= off) ? sc[t - off] : 0;
    __syncthreads();
    if (t < DPB) sc[t] += u;
    __syncthreads();
  }
  if (t < DPB) {
    int ex = sc[t] - h[t];
    cur[t] = ex;
    int d = dbase + t;
    if (d < N) row_ptr[d] = beg + ex;
  }
  if (b == 0 && t == 0) row_ptr[N] = E;
  __syncthreads();
  for (int k = beg + t; k < end; k += 256) {
    unsigned int r = binned[k];
    int pos = beg + atomicAdd(&cur[r & (DPB - 1)], 1);
    sorted[pos] = r;
  }
}

// ---------------------------------------------------------------------------
// gather: out[n][:] (+relu) += sum_{in-edges} h[rel][src][:]
// 8 lanes per node, 16B per lane, 2-edge unroll, register accumulate.
// record: rel<<24 | src<<7 | ldst
// ---------------------------------------------------------------------------
__global__ __launch_bounds__(256) void rgcn_gather(
    const unsigned int* __restrict__ sorted,
    const int* __restrict__ row_ptr,
    const unsigned short* __restrict__ hb,
    float* __restrict__ out,
    int N, int do_relu)
{
  const int t = threadIdx.x;
  const int node = blockIdx.x * 32 + (t >> 3);
  if (node >= N) return;
  const int l8 = (t & 7) * 8;

  int p = row_ptr[node];
  const int pe = row_ptr[node + 1];

  float acc[8];
#pragma unroll
  for (int i = 0; i < 8; ++i) acc[i] = 0.f;

  for (; p + 1 < pe; p += 2) {
    unsigned wa = sorted[p], wb = sorted[p + 1];
    uint4 ua = *(const uint4*)&hb[
        (((size_t)(wa >> 24) * N + ((wa >> 7) & 0x1FFFFu)) << 6) + l8];
    uint4 ub = *(const uint4*)&hb[
        (((size_t)(wb >> 24) * N + ((wb >> 7) & 0x1FFFFu)) << 6) + l8];
    acc[0] += bf2f((unsigned short)ua.x) + bf2f((unsigned short)ub.x);
    acc[1] += bf2f((unsigned short)(ua.x >> 16)) + bf2f((unsigned short)(ub.x >> 16));
    acc[2] += bf2f((unsigned short)ua.y) + bf2f((unsigned short)ub.y);
    acc[3] += bf2f((unsigned short)(ua.y >> 16)) + bf2f((unsigned short)(ub.y >> 16));
    acc[4] += bf2f((unsigned short)ua.z) + bf2f((unsigned short)ub.z);
    acc[5] += bf2f((unsigned short)(ua.z >> 16)) + bf2f((unsigned short)(ub.z >> 16));
    acc[6] += bf2f((unsigned short)ua.w) + bf2f((unsigned short)ub.w);
    acc[7] += bf2f((unsigned short)(ua.w >> 16)) + bf2f((unsigned short)(ub.w >> 16));
  }
  if (p < pe) {
    unsigned wa = sorted[p];
    uint4 ua = *(const uint4*)&hb[
        (((size_t)(wa >> 24) * N + ((wa >> 7) & 0x1FFFFu)) << 6) + l8];
    acc[0] += bf2f((unsigned short)ua.x);
    acc[1] += bf2f((unsigned short)(ua.x >> 16));
    acc[2] += bf2f((unsigned short)ua.y);
    acc[3] += bf2f((unsigned short)(ua.y >> 16));
    acc[4] += bf2f((unsigned short)ua.z);
    acc[5] += bf2f((unsigned short)(ua.z >> 16));
    acc[6] += bf2f((unsigned short)ua.w);
    acc[7] += bf2f((unsigned short)(ua.w >> 16));
  }

  float* o = out + ((size_t)node << 6) + l8;
  float4 c0 = *(float4*)o;
  float4 c1 = *(float4*)(o + 4);
  c0.x += acc[0]; c0.y += acc[1]; c0.z += acc[2]; c0.w += acc[3];
  c1.x += acc[4]; c1.y += acc[5]; c1.z += acc[6]; c1.w += acc[7];
  if (do_relu) {
    c0.x = fmaxf(c0.x, 0.f); c0.y = fmaxf(c0.y, 0.f);
    c0.z = fmaxf(c0.z, 0.f); c0.w = fmaxf(c0.w, 0.f);
    c1.x = fmaxf(c1.x, 0.f); c1.y = fmaxf(c1.y, 0.f);
    c1.z = fmaxf(c1.z, 0.f); c1.w = fmaxf(c1.w, 0.f);
  }
  *(float4*)o = c0;
  *(float4*)(o + 4) = c1;
}

// ---------------------------------------------------------------------------
// fallback atomic scatter (bf16 h) — only if ws too small for CSR path
// ---------------------------------------------------------------------------
__global__ __launch_bounds__(256) void rgcn_scatter(
    const int* __restrict__ src, const int* __restrict__ dst,
    const int* __restrict__ et,
    const unsigned short* __restrict__ hb,
    float* __restrict__ out,
    int E, int N, int r0, int r1)
{
  long long g = (long long)blockIdx.x * 256 + threadIdx.x;
  int e = (int)(g >> 4);
  if (e >= E) return;
  int r = et[e];
  if (r < r0 || r >= r1) return;
  int f4 = ((int)g & 15) * 4;
  int s = src[e];
  int d = dst[e];
  ushort4 u = *(const ushort4*)&hb[(((size_t)(r - r0) * N + s) << 6) + f4];
  float* o = out + ((size_t)d << 6) + f4;
  atomicAdd(o + 0, bf2f(u.x));
  atomicAdd(o + 1, bf2f(u.y));
  atomicAdd(o + 2, bf2f(u.z));
  atomicAdd(o + 3, bf2f(u.w));
}

// ---------------------------------------------------------------------------
extern "C" void kernel_launch(void* const* d_in, const int* in_sizes, int n_in,
                              void* d_out, int out_size, void* d_ws, size_t ws_size,
                              hipStream_t stream) {
  const int* adj    = (const int*)d_in[0];    // [2, E]
  const float* feat = (const float*)d_in[1];  // [N, 64]
  const int* et     = (const int*)d_in[2];    // [E]
  const float* W1   = (const float*)d_in[3];
  const float* rt1  = (const float*)d_in[4];
  const float* b1   = (const float*)d_in[5];
  const float* W2   = (const float*)d_in[6];
  const float* rt2  = (const float*)d_in[7];
  const float* b2   = (const float*)d_in[8];

  const int E = in_sizes[0] / 2;
  const int N = in_sizes[1] / DF;
  const int* srcp = adj;
  const int* dstp = adj + E;

  float* out = (float*)d_out;
  const size_t ND = (size_t)N * DF;
  const int nblk = (N + 127) / 128;
  const int NB = (N + DPB - 1) >> DPB_SHIFT;

  // ws layout: hb bf16[8,N,64] | xb bf16[N,64] | wfrag | binned u32[E] |
  //            sorted u32[E] | row_ptr[N+1] | bcnt[NB] | boff[NB+1] | bcur[NB]
  const size_t wfrag_elems = (size_t)16 * 8 * 64;  // bf16x8 units
  const size_t need_csr = 8 * ND * 2 + ND * 2 + wfrag_elems * 16 +
                          (size_t)E * 4 + (size_t)E * 4 +
                          ((size_t)N + 1) * 4 + ((size_t)3 * NB + 1) * 4;

  if (ws_size >= need_csr && NB <= NBMAX && N < (1 << 17)) {
    unsigned short* hb = (unsigned short*)d_ws;
    unsigned short* xb = hb + 8 * ND;
    bf16x8* wfrag = (bf16x8*)(xb + ND);
    unsigned int* binned = (unsigned int*)(wfrag + wfrag_elems);
    unsigned int* sorted = binned + E;
    int* row_ptr = (int*)(sorted + E);
    int* bcnt = row_ptr + (N + 1);
    int* boff = bcnt + NB;
    int* bcur = boff + (NB + 1);

    // ---- build per-node-grouped edge list once (same graph both layers) ----
    const int ebk = (E + EPB - 1) / EPB;
    zero_ints<<<(NB + 255) / 256, 256, 0, stream>>>(bcnt, NB);
    bucket_count<<<ebk, 256, 0, stream>>>(dstp, bcnt, E, NB);
    scan_buckets<<<1, 1024, 0, stream>>>(bcnt, boff, bcur, NB, E);
    bin_scatter<<<ebk, 256, 0, stream>>>(srcp, dstp, et, bcur, binned, E, NB);
    fill_bucket<<<NB, 256, 0, stream>>>(binned, boff, row_ptr, sorted, N, E);

    // ---- pack weights into MFMA fragments (both layers) ----
    pack_wfrag<<<16, 512, 0, stream>>>(W1, W2, wfrag);

    const int gblk = (N + 31) / 32;

    // ---- layer 1: out = relu( agg(h1) + feat@rt1 + b1 ) ----
    rgcn_root_epilogue<<<nblk, 128, 0, stream>>>(feat, rt1, b1, out, xb, N, 0);
    mfma_transform<<<nblk, 256, 0, stream>>>(xb, wfrag, hb, N);
    rgcn_gather<<<gblk, 256, 0, stream>>>(sorted, row_ptr, hb, out, N, 1);

    // ---- layer 2: out = agg(h2) + out@rt2 + b2 ----
    rgcn_root_epilogue<<<nblk, 128, 0, stream>>>(out, rt2, b2, out, xb, N, 0);
    mfma_transform<<<nblk, 256, 0, stream>>>(xb, wfrag + (size_t)8 * 8 * 64, hb, N);
    rgcn_gather<<<gblk, 256, 0, stream>>>(sorted, row_ptr, hb, out, N, 0);
    return;
  }

  // ---------------- fallback: atomic scatter ----------------
  size_t per_rel = ND * sizeof(unsigned short);
  size_t xmid_b = ND * sizeof(float);
  int RC = 1;
  if (ws_size > per_rel + xmid_b) {
    size_t rc = (ws_size - xmid_b) / per_rel;
    RC = rc >= NREL ? NREL : (int)rc;
  }
  unsigned short* hb = (unsigned short*)d_ws;
  float* xmid = (float*)((char*)d_ws + (size_t)RC * per_rel);
  const int sblk = (int)(((size_t)E * 16 + 255) / 256);

  for (int layer = 0; layer < 2; ++layer) {
    const float* xin = layer ? xmid : feat;
    const float* W   = layer ? W2 : W1;
    const float* rt  = layer ? rt2 : rt1;
    const float* bs  = layer ? b2 : b1;
    float* o         = layer ? out : xmid;

    hipMemsetAsync(o, 0, ND * sizeof(float), stream);
    for (int r0 = 0; r0 < NREL; r0 += RC) {
      int rc = (NREL - r0) < RC ? (NREL - r0) : RC;
      rgcn_transform<<<dim3(nblk, rc), 128, 0, stream>>>(
          xin, W + (size_t)r0 * DF * DF, hb, N);
      rgcn_scatter<<<sblk, 256, 0, stream>>>(
          srcp, dstp, et, hb, o, E, N, r0, r0 + rc);
    }
    rgcn_root_epilogue<<<nblk, 128, 0, stream>>>(xin, rt, bs, o, nullptr, N,
                                                 layer == 0 ? 1 : 2);
  }
}

// Round 8
// 197.410 us; speedup vs baseline: 7.5253x; 1.1136x over previous
//
#include <hip/hip_runtime.h>
#include <cstdint>
#include <cstddef>

#define DF 64          // feature dim
#define NREL 8         // relations
#define DPB 128        // dst nodes per coarse bucket
#define DPB_SHIFT 7
#define NBMAX 1024     // max coarse buckets supported by LDS kernels
#define EPB 2048       // edges per binning block

typedef __attribute__((ext_vector_type(8))) short bf16x8;
typedef __attribute__((ext_vector_type(4))) float f32x4;

// ---- bf16 helpers (RNE) ---------------------------------------------------
static __device__ __forceinline__ unsigned short f2bf(float f) {
  unsigned int u = __float_as_uint(f);
  u += 0x7FFFu + ((u >> 16) & 1u);
  return (unsigned short)(u >> 16);
}
static __device__ __forceinline__ float bf2f(unsigned short s) {
  return __uint_as_float((unsigned int)s << 16);
}

// ---------------------------------------------------------------------------
// pack weights into bf16 MFMA B-fragments. 18 mats:
//   0..7 = W1 rels, 8 = root1, 9..16 = W2 rels, 17 = root2
// frag[((mat*4 + nt)*2 + ks)*64 + l] = { W[ks*32 + (l>>4)*8 + j][nt*16 + (l&15)] }
// ---------------------------------------------------------------------------
__global__ __launch_bounds__(512) void pack_wfrag(
    const float* __restrict__ W1, const float* __restrict__ rt1,
    const float* __restrict__ W2, const float* __restrict__ rt2,
    bf16x8* __restrict__ frag)
{
  const int mat = blockIdx.x;    // 0..17
  const float* W = (mat < 8)  ? (W1 + (size_t)mat * 4096)
                 : (mat == 8) ? rt1
                 : (mat < 17) ? (W2 + (size_t)(mat - 9) * 4096)
                              : rt2;
  const int idx = threadIdx.x;   // 0..511
  const int nt = idx >> 7;
  const int ks = (idx >> 6) & 1;
  const int l  = idx & 63;
  const int col = nt * 16 + (l & 15);
  const int k0  = ks * 32 + (l >> 4) * 8;
  bf16x8 f;
#pragma unroll
  for (int j = 0; j < 8; ++j)
    f[j] = (short)f2bf(W[(size_t)(k0 + j) * 64 + col]);
  frag[(((size_t)mat * 4 + nt) * 2 + ks) * 64 + l] = f;
}

// ---------------------------------------------------------------------------
// Fused MFMA transform: reads fp32 x, converts A-frags in-register.
//   r = 0..7 : hb[r][n][f] = bf16( x @ W[r] )
//   r = 8    : out[n][f]   = fp32( x @ root ) + bias   (overwrite)
// block = 256 thr = 4 waves; block tile = 128 nodes; wave tile = 32 nodes.
// ---------------------------------------------------------------------------
__global__ __launch_bounds__(256) void mfma_transform(
    const float* __restrict__ x,             // [N][64] fp32
    const bf16x8* __restrict__ wfrag,        // [9][4][2][64] (layer base)
    const float* __restrict__ bias,          // [64]
    unsigned short* __restrict__ hb,         // [8][N][64] bf16
    float* __restrict__ out,                 // [N][64] fp32
    int N)
{
  const int tid = threadIdx.x;
  const int l  = tid & 63;
  const int w  = tid >> 6;
  const int n0 = blockIdx.x * 128 + w * 32;
  const int lr = l & 15;   // A row / B col within 16-tile
  const int lg = l >> 4;   // k-group

  bf16x8 a[2][2];
#pragma unroll
  for (int mt = 0; mt < 2; ++mt) {
    const int row = n0 + mt * 16 + lr;
#pragma unroll
    for (int ks = 0; ks < 2; ++ks) {
      if (row < N) {
        const float* xp = &x[(size_t)row * 64 + ks * 32 + lg * 8];
        float4 v0 = *(const float4*)xp;
        float4 v1 = *(const float4*)(xp + 4);
        bf16x8 t;
        t[0] = (short)f2bf(v0.x); t[1] = (short)f2bf(v0.y);
        t[2] = (short)f2bf(v0.z); t[3] = (short)f2bf(v0.w);
        t[4] = (short)f2bf(v1.x); t[5] = (short)f2bf(v1.y);
        t[6] = (short)f2bf(v1.z); t[7] = (short)f2bf(v1.w);
        a[mt][ks] = t;
      } else {
        a[mt][ks] = (bf16x8)(short)0;
      }
    }
  }

  float bb[4];
#pragma unroll
  for (int nt = 0; nt < 4; ++nt) bb[nt] = bias[nt * 16 + lr];

  for (int r = 0; r < 9; ++r) {
    const bf16x8* wf = wfrag + (size_t)r * 512;
    bf16x8 b[4][2];
#pragma unroll
    for (int nt = 0; nt < 4; ++nt)
#pragma unroll
      for (int ks = 0; ks < 2; ++ks)
        b[nt][ks] = wf[(nt * 2 + ks) * 64 + l];

    f32x4 acc[2][4];
#pragma unroll
    for (int mt = 0; mt < 2; ++mt)
#pragma unroll
      for (int nt = 0; nt < 4; ++nt)
        acc[mt][nt] = (f32x4)(0.f);

#pragma unroll
    for (int ks = 0; ks < 2; ++ks)
#pragma unroll
      for (int mt = 0; mt < 2; ++mt)
#pragma unroll
        for (int nt = 0; nt < 4; ++nt)
          acc[mt][nt] = __builtin_amdgcn_mfma_f32_16x16x32_bf16(
              a[mt][ks], b[nt][ks], acc[mt][nt], 0, 0, 0);

    if (r < 8) {
      unsigned short* hr = hb + (size_t)r * N * 64;
#pragma unroll
      for (int mt = 0; mt < 2; ++mt) {
#pragma unroll
        for (int i = 0; i < 4; ++i) {
          const int node = n0 + mt * 16 + lg * 4 + i;
          if (node < N) {
            unsigned short* o = hr + (size_t)node * 64 + lr;
#pragma unroll
            for (int nt = 0; nt < 4; ++nt)
              o[nt * 16] = f2bf(acc[mt][nt][i]);
          }
        }
      }
    } else {
#pragma unroll
      for (int mt = 0; mt < 2; ++mt) {
#pragma unroll
        for (int i = 0; i < 4; ++i) {
          const int node = n0 + mt * 16 + lg * 4 + i;
          if (node < N) {
            float* o = out + (size_t)node * 64 + lr;
#pragma unroll
            for (int nt = 0; nt < 4; ++nt)
              o[nt * 16] = acc[mt][nt][i] + bb[nt];
          }
        }
      }
    }
  }
}

// ---------------------------------------------------------------------------
// fp32 vector transform (FALLBACK path only)
// ---------------------------------------------------------------------------
__global__ __launch_bounds__(128) void rgcn_transform(
    const float* __restrict__ x,
    const float* __restrict__ Wc,
    unsigned short* __restrict__ hb,
    int N)
{
  const int r = blockIdx.y;
  const float* W = Wc + (size_t)r * DF * DF;

  __shared__ float Ws[DF * DF];
  __shared__ float Xs[128 * 65];

  const int tid = threadIdx.x;
  const int n0 = blockIdx.x * 128;
  const int nrem = N - n0;

  {
    const float4* Wv = (const float4*)W;
    float4* Wsv = (float4*)Ws;
#pragma unroll
    for (int j = 0; j < 8; ++j) Wsv[tid + j * 128] = Wv[tid + j * 128];
  }
#pragma unroll
  for (int j = 0; j < 16; ++j) {
    int idx = tid + j * 128;
    int n = idx >> 4;
    int c4 = (idx & 15) * 4;
    float4 v = make_float4(0.f, 0.f, 0.f, 0.f);
    if (n < nrem) v = *(const float4*)&x[(size_t)(n0 + n) * DF + c4];
    float* p = &Xs[n * 65 + c4];
    p[0] = v.x; p[1] = v.y; p[2] = v.z; p[3] = v.w;
  }
  __syncthreads();

  const int fg = (tid & 7) * 8;
  const int ng = (tid >> 3) * 8;

  float4 a0[8], a1[8];
#pragma unroll
  for (int i = 0; i < 8; ++i) {
    a0[i] = make_float4(0.f, 0.f, 0.f, 0.f);
    a1[i] = make_float4(0.f, 0.f, 0.f, 0.f);
  }

#pragma unroll 4
  for (int d = 0; d < DF; ++d) {
    float4 w0 = *(const float4*)&Ws[d * DF + fg];
    float4 w1 = *(const float4*)&Ws[d * DF + fg + 4];
#pragma unroll
    for (int i = 0; i < 8; ++i) {
      float xv = Xs[(ng + i) * 65 + d];
      a0[i].x += xv * w0.x; a0[i].y += xv * w0.y;
      a0[i].z += xv * w0.z; a0[i].w += xv * w0.w;
      a1[i].x += xv * w1.x; a1[i].y += xv * w1.y;
      a1[i].z += xv * w1.z; a1[i].w += xv * w1.w;
    }
  }

#pragma unroll
  for (int i = 0; i < 8; ++i) {
    int n = ng + i;
    if (n < nrem) {
      uint4 pk;
      pk.x = (unsigned)f2bf(a0[i].x) | ((unsigned)f2bf(a0[i].y) << 16);
      pk.y = (unsigned)f2bf(a0[i].z) | ((unsigned)f2bf(a0[i].w) << 16);
      pk.z = (unsigned)f2bf(a1[i].x) | ((unsigned)f2bf(a1[i].y) << 16);
      pk.w = (unsigned)f2bf(a1[i].z) | ((unsigned)f2bf(a1[i].w) << 16);
      unsigned short* op = hb + (((size_t)r * N + (n0 + n)) << 6) + fg;
      *(uint4*)op = pk;
    }
  }
}

// ---------------------------------------------------------------------------
// fp32 root epilogue (FALLBACK path only)
//   mode 1: out = relu(out + x@root + b) ; mode 2: out = out + x@root + b
// ---------------------------------------------------------------------------
__global__ __launch_bounds__(128) void rgcn_root_epilogue(
    const float* __restrict__ x,
    const float* __restrict__ root,
    const float* __restrict__ bias,
    float* __restrict__ out,
    int N, int mode)
{
  __shared__ float Ws[DF * DF];
  __shared__ float Xs[128 * 65];

  const int tid = threadIdx.x;
  const int n0 = blockIdx.x * 128;
  const int nrem = N - n0;

  {
    const float4* Wv = (const float4*)root;
    float4* Wsv = (float4*)Ws;
#pragma unroll
    for (int j = 0; j < 8; ++j) Wsv[tid + j * 128] = Wv[tid + j * 128];
  }
#pragma unroll
  for (int j = 0; j < 16; ++j) {
    int idx = tid + j * 128;
    int n = idx >> 4;
    int c4 = (idx & 15) * 4;
    float4 v = make_float4(0.f, 0.f, 0.f, 0.f);
    if (n < nrem) v = *(const float4*)&x[(size_t)(n0 + n) * DF + c4];
    float* p = &Xs[n * 65 + c4];
    p[0] = v.x; p[1] = v.y; p[2] = v.z; p[3] = v.w;
  }
  __syncthreads();

  const int fg = (tid & 7) * 8;
  const int ng = (tid >> 3) * 8;

  float4 a0[8], a1[8];
#pragma unroll
  for (int i = 0; i < 8; ++i) {
    a0[i] = make_float4(0.f, 0.f, 0.f, 0.f);
    a1[i] = make_float4(0.f, 0.f, 0.f, 0.f);
  }

#pragma unroll 4
  for (int d = 0; d < DF; ++d) {
    float4 w0 = *(const float4*)&Ws[d * DF + fg];
    float4 w1 = *(const float4*)&Ws[d * DF + fg + 4];
#pragma unroll
    for (int i = 0; i < 8; ++i) {
      float xv = Xs[(ng + i) * 65 + d];
      a0[i].x += xv * w0.x; a0[i].y += xv * w0.y;
      a0[i].z += xv * w0.z; a0[i].w += xv * w0.w;
      a1[i].x += xv * w1.x; a1[i].y += xv * w1.y;
      a1[i].z += xv * w1.z; a1[i].w += xv * w1.w;
    }
  }

  float4 bb0 = *(const float4*)&bias[fg];
  float4 bb1 = *(const float4*)&bias[fg + 4];

#pragma unroll
  for (int i = 0; i < 8; ++i) {
    int n = ng + i;
    if (n < nrem) {
      float* op = out + (size_t)(n0 + n) * DF + fg;
      float4 o0 = *(float4*)op;
      float4 o1 = *(float4*)(op + 4);
      o0.x += a0[i].x + bb0.x; o0.y += a0[i].y + bb0.y;
      o0.z += a0[i].z + bb0.z; o0.w += a0[i].w + bb0.w;
      o1.x += a1[i].x + bb1.x; o1.y += a1[i].y + bb1.y;
      o1.z += a1[i].z + bb1.z; o1.w += a1[i].w + bb1.w;
      if (mode == 1) {
        o0.x = fmaxf(o0.x, 0.f); o0.y = fmaxf(o0.y, 0.f);
        o0.z = fmaxf(o0.z, 0.f); o0.w = fmaxf(o0.w, 0.f);
        o1.x = fmaxf(o1.x, 0.f); o1.y = fmaxf(o1.y, 0.f);
        o1.z = fmaxf(o1.z, 0.f); o1.w = fmaxf(o1.w, 0.f);
      }
      *(float4*)op = o0;
      *(float4*)(op + 4) = o1;
    }
  }
}

// ---------------------------------------------------------------------------
// CSR build: zero -> bucket_count -> scan -> bin_scatter -> fill_bucket
// record (u32): rel[3] << 24 | src[17] << 7 | local_dst[7]
// ---------------------------------------------------------------------------
__global__ __launch_bounds__(256) void zero_ints(int* __restrict__ p, int n)
{
  int i = blockIdx.x * 256 + threadIdx.x;
  if (i < n) p[i] = 0;
}

__global__ __launch_bounds__(256) void bucket_count(
    const int* __restrict__ dst, int* __restrict__ bcnt, int E, int NB)
{
  __shared__ int lh[NBMAX];
  const int t = threadIdx.x;
  for (int i = t; i < NB; i += 256) lh[i] = 0;
  __syncthreads();
  const int base = blockIdx.x * EPB;
  const int cnt = min(EPB, E - base);
  for (int k = t; k < cnt; k += 256)
    atomicAdd(&lh[dst[base + k] >> DPB_SHIFT], 1);
  __syncthreads();
  for (int i = t; i < NB; i += 256) {
    int c = lh[i];
    if (c) atomicAdd(&bcnt[i], c);
  }
}

__global__ __launch_bounds__(1024) void scan_buckets(
    const int* __restrict__ bcnt, int* __restrict__ boff,
    int* __restrict__ bcur, int NB, int E)
{
  __shared__ int sc[1024];
  const int t = threadIdx.x;
  int v = (t < NB) ? bcnt[t] : 0;
  sc[t] = v;
  __syncthreads();
  for (int off = 1; off < 1024; off <<= 1) {
    int u = (t >= off) ? sc[t - off] : 0;
    __syncthreads();
    sc[t] += u;
    __syncthreads();
  }
  if (t < NB) {
    int ex = sc[t] - v;
    boff[t] = ex;
    bcur[t] = ex;
  }
  if (t == 0) boff[NB] = E;
}

__global__ __launch_bounds__(256) void bin_scatter(
    const int* __restrict__ src, const int* __restrict__ dst,
    const int* __restrict__ et, int* __restrict__ bcur,
    unsigned int* __restrict__ binned, int E, int NB)
{
  __shared__ int lh[NBMAX];
  const int t = threadIdx.x;
  for (int i = t; i < NB; i += 256) lh[i] = 0;
  __syncthreads();
  const int base = blockIdx.x * EPB;
  const int cnt = min(EPB, E - base);
  for (int k = t; k < cnt; k += 256)
    atomicAdd(&lh[dst[base + k] >> DPB_SHIFT], 1);
  __syncthreads();
  for (int i = t; i < NB; i += 256) {
    int c = lh[i];
    lh[i] = c ? atomicAdd(&bcur[i], c) : 0;
  }
  __syncthreads();
  for (int k = t; k < cnt; k += 256) {
    int e = base + k;
    int d = dst[e];
    int pos = atomicAdd(&lh[d >> DPB_SHIFT], 1);
    binned[pos] = ((unsigned)et[e] << 24) | ((unsigned)src[e] << 7) |
                  ((unsigned)d & (DPB - 1));
  }
}

// per-bucket local count/scan/scatter -> row_ptr + per-node-grouped records
__global__ __launch_bounds__(512) void fill_bucket(
    const unsigned int* __restrict__ binned, const int* __restrict__ boff,
    int* __restrict__ row_ptr, unsigned int* __restrict__ sorted,
    int N, int E)
{
  __shared__ int h[DPB];
  __shared__ int sc[DPB];
  __shared__ int cur[DPB];
  const int t = threadIdx.x;
  const int b = blockIdx.x;
  const int beg = boff[b], end = boff[b + 1];
  const int dbase = b << DPB_SHIFT;

  if (t < DPB) h[t] = 0;
  __syncthreads();
  for (int k = beg + t; k < end; k += 512)
    atomicAdd(&h[binned[k] & (DPB - 1)], 1);
  __syncthreads();
  if (t < DPB) sc[t] = h[t];
  __syncthreads();
  for (int off = 1; off < DPB; off <<= 1) {
    int u = (t < DPB && t >= off) ? sc[t - off] : 0;
    __syncthreads();
    if (t < DPB) sc[t] += u;
    __syncthreads();
  }
  if (t < DPB) {
    int ex = sc[t] - h[t];
    cur[t] = ex;
    int d = dbase + t;
    if (d < N) row_ptr[d] = beg + ex;
  }
  if (b == 0 && t == 0) row_ptr[N] = E;
  __syncthreads();
  for (int k = beg + t; k < end; k += 512) {
    unsigned int r = binned[k];
    int pos = beg + atomicAdd(&cur[r & (DPB - 1)], 1);
    sorted[pos] = r;
  }
}

// ---------------------------------------------------------------------------
// gather: out[n][:] (+relu) += sum_{in-edges} h[rel][src][:]
// 8 lanes per node, 16B per lane, 4-edge unroll, register accumulate.
// record: rel<<24 | src<<7 | ldst
// ---------------------------------------------------------------------------
static __device__ __forceinline__ void gadd(
    float* __restrict__ acc, const uint4& u)
{
  acc[0] += bf2f((unsigned short)u.x);
  acc[1] += bf2f((unsigned short)(u.x >> 16));
  acc[2] += bf2f((unsigned short)u.y);
  acc[3] += bf2f((unsigned short)(u.y >> 16));
  acc[4] += bf2f((unsigned short)u.z);
  acc[5] += bf2f((unsigned short)(u.z >> 16));
  acc[6] += bf2f((unsigned short)u.w);
  acc[7] += bf2f((unsigned short)(u.w >> 16));
}

__global__ __launch_bounds__(256) void rgcn_gather(
    const unsigned int* __restrict__ sorted,
    const int* __restrict__ row_ptr,
    const unsigned short* __restrict__ hb,
    float* __restrict__ out,
    int N, int do_relu)
{
  const int t = threadIdx.x;
  const int node = blockIdx.x * 32 + (t >> 3);
  if (node >= N) return;
  const int l8 = (t & 7) * 8;

  int p = row_ptr[node];
  const int pe = row_ptr[node + 1];

  float acc[8];
#pragma unroll
  for (int i = 0; i < 8; ++i) acc[i] = 0.f;

  for (; p + 3 < pe; p += 4) {
    unsigned w0 = sorted[p],     w1 = sorted[p + 1];
    unsigned w2 = sorted[p + 2], w3 = sorted[p + 3];
    uint4 u0 = *(const uint4*)&hb[(((size_t)(w0 >> 24) * N + ((w0 >> 7) & 0x1FFFFu)) << 6) + l8];
    uint4 u1 = *(const uint4*)&hb[(((size_t)(w1 >> 24) * N + ((w1 >> 7) & 0x1FFFFu)) << 6) + l8];
    uint4 u2 = *(const uint4*)&hb[(((size_t)(w2 >> 24) * N + ((w2 >> 7) & 0x1FFFFu)) << 6) + l8];
    uint4 u3 = *(const uint4*)&hb[(((size_t)(w3 >> 24) * N + ((w3 >> 7) & 0x1FFFFu)) << 6) + l8];
    gadd(acc, u0); gadd(acc, u1); gadd(acc, u2); gadd(acc, u3);
  }
  for (; p < pe; ++p) {
    unsigned w0 = sorted[p];
    uint4 u0 = *(const uint4*)&hb[(((size_t)(w0 >> 24) * N + ((w0 >> 7) & 0x1FFFFu)) << 6) + l8];
    gadd(acc, u0);
  }

  float* o = out + ((size_t)node << 6) + l8;
  float4 c0 = *(float4*)o;
  float4 c1 = *(float4*)(o + 4);
  c0.x += acc[0]; c0.y += acc[1]; c0.z += acc[2]; c0.w += acc[3];
  c1.x += acc[4]; c1.y += acc[5]; c1.z += acc[6]; c1.w += acc[7];
  if (do_relu) {
    c0.x = fmaxf(c0.x, 0.f); c0.y = fmaxf(c0.y, 0.f);
    c0.z = fmaxf(c0.z, 0.f); c0.w = fmaxf(c0.w, 0.f);
    c1.x = fmaxf(c1.x, 0.f); c1.y = fmaxf(c1.y, 0.f);
    c1.z = fmaxf(c1.z, 0.f); c1.w = fmaxf(c1.w, 0.f);
  }
  *(float4*)o = c0;
  *(float4*)(o + 4) = c1;
}

// ---------------------------------------------------------------------------
// fallback atomic scatter (bf16 h) — only if ws too small for CSR path
// ---------------------------------------------------------------------------
__global__ __launch_bounds__(256) void rgcn_scatter(
    const int* __restrict__ src, const int* __restrict__ dst,
    const int* __restrict__ et,
    const unsigned short* __restrict__ hb,
    float* __restrict__ out,
    int E, int N, int r0, int r1)
{
  long long g = (long long)blockIdx.x * 256 + threadIdx.x;
  int e = (int)(g >> 4);
  if (e >= E) return;
  int r = et[e];
  if (r < r0 || r >= r1) return;
  int f4 = ((int)g & 15) * 4;
  int s = src[e];
  int d = dst[e];
  ushort4 u = *(const ushort4*)&hb[(((size_t)(r - r0) * N + s) << 6) + f4];
  float* o = out + ((size_t)d << 6) + f4;
  atomicAdd(o + 0, bf2f(u.x));
  atomicAdd(o + 1, bf2f(u.y));
  atomicAdd(o + 2, bf2f(u.z));
  atomicAdd(o + 3, bf2f(u.w));
}

// ---------------------------------------------------------------------------
extern "C" void kernel_launch(void* const* d_in, const int* in_sizes, int n_in,
                              void* d_out, int out_size, void* d_ws, size_t ws_size,
                              hipStream_t stream) {
  const int* adj    = (const int*)d_in[0];    // [2, E]
  const float* feat = (const float*)d_in[1];  // [N, 64]
  const int* et     = (const int*)d_in[2];    // [E]
  const float* W1   = (const float*)d_in[3];
  const float* rt1  = (const float*)d_in[4];
  const float* b1   = (const float*)d_in[5];
  const float* W2   = (const float*)d_in[6];
  const float* rt2  = (const float*)d_in[7];
  const float* b2   = (const float*)d_in[8];

  const int E = in_sizes[0] / 2;
  const int N = in_sizes[1] / DF;
  const int* srcp = adj;
  const int* dstp = adj + E;

  float* out = (float*)d_out;
  const size_t ND = (size_t)N * DF;
  const int nblk = (N + 127) / 128;
  const int NB = (N + DPB - 1) >> DPB_SHIFT;

  // ws layout: hb bf16[8,N,64] | wfrag[18*512 bf16x8] | binned u32[E] |
  //            sorted u32[E] | row_ptr[N+1] | bcnt[NB] | boff[NB+1] | bcur[NB]
  const size_t wfrag_elems = (size_t)18 * 512;  // bf16x8 units
  const size_t need_csr = 8 * ND * 2 + wfrag_elems * 16 +
                          (size_t)E * 4 + (size_t)E * 4 +
                          ((size_t)N + 1) * 4 + ((size_t)3 * NB + 1) * 4;

  if (ws_size >= need_csr && NB <= NBMAX && N < (1 << 17)) {
    unsigned short* hb = (unsigned short*)d_ws;
    bf16x8* wfrag = (bf16x8*)(hb + 8 * ND);
    unsigned int* binned = (unsigned int*)(wfrag + wfrag_elems);
    unsigned int* sorted = binned + E;
    int* row_ptr = (int*)(sorted + E);
    int* bcnt = row_ptr + (N + 1);
    int* boff = bcnt + NB;
    int* bcur = boff + (NB + 1);

    // ---- build per-node-grouped edge list once (same graph both layers) ----
    const int ebk = (E + EPB - 1) / EPB;
    zero_ints<<<(NB + 255) / 256, 256, 0, stream>>>(bcnt, NB);
    bucket_count<<<ebk, 256, 0, stream>>>(dstp, bcnt, E, NB);
    scan_buckets<<<1, 1024, 0, stream>>>(bcnt, boff, bcur, NB, E);
    bin_scatter<<<ebk, 256, 0, stream>>>(srcp, dstp, et, bcur, binned, E, NB);
    fill_bucket<<<NB, 512, 0, stream>>>(binned, boff, row_ptr, sorted, N, E);

    // ---- pack weights into MFMA fragments (both layers + roots) ----
    pack_wfrag<<<18, 512, 0, stream>>>(W1, rt1, W2, rt2, wfrag);

    const int gblk = (N + 31) / 32;

    // ---- layer 1: out = relu( agg(h1) + feat@rt1 + b1 ) ----
    mfma_transform<<<nblk, 256, 0, stream>>>(feat, wfrag, b1, hb, out, N);
    rgcn_gather<<<gblk, 256, 0, stream>>>(sorted, row_ptr, hb, out, N, 1);

    // ---- layer 2: out = agg(h2) + out@rt2 + b2 ----
    mfma_transform<<<nblk, 256, 0, stream>>>(out, wfrag + (size_t)9 * 512, b2, hb, out, N);
    rgcn_gather<<<gblk, 256, 0, stream>>>(sorted, row_ptr, hb, out, N, 0);
    return;
  }

  // ---------------- fallback: atomic scatter ----------------
  size_t per_rel = ND * sizeof(unsigned short);
  size_t xmid_b = ND * sizeof(float);
  int RC = 1;
  if (ws_size > per_rel + xmid_b) {
    size_t rc = (ws_size - xmid_b) / per_rel;
    RC = rc >= NREL ? NREL : (int)rc;
  }
  unsigned short* hb = (unsigned short*)d_ws;
  float* xmid = (float*)((char*)d_ws + (size_t)RC * per_rel);
  const int sblk = (int)(((size_t)E * 16 + 255) / 256);

  for (int layer = 0; layer < 2; ++layer) {
    const float* xin = layer ? xmid : feat;
    const float* W   = layer ? W2 : W1;
    const float* rt  = layer ? rt2 : rt1;
    const float* bs  = layer ? b2 : b1;
    float* o         = layer ? out : xmid;

    hipMemsetAsync(o, 0, ND * sizeof(float), stream);
    for (int r0 = 0; r0 < NREL; r0 += RC) {
      int rc = (NREL - r0) < RC ? (NREL - r0) : RC;
      rgcn_transform<<<dim3(nblk, rc), 128, 0, stream>>>(
          xin, W + (size_t)r0 * DF * DF, hb, N);
      rgcn_scatter<<<sblk, 256, 0, stream>>>(
          srcp, dstp, et, hb, o, E, N, r0, r0 + rc);
    }
    rgcn_root_epilogue<<<nblk, 128, 0, stream>>>(xin, rt, bs, o, N,
                                                 layer == 0 ? 1 : 2);
  }
}

// Round 9
// 187.037 us; speedup vs baseline: 7.9426x; 1.0555x over previous
//
#include <hip/hip_runtime.h>
#include <cstdint>
#include <cstddef>

#define DF 64          // feature dim
#define NREL 8         // relations
#define DPB 64         // dst nodes per coarse bucket
#define DPB_SHIFT 6
#define NBMAX 1024     // max coarse buckets supported by LDS kernels
#define EPB 2048       // edges per binning block
#define BCAP 3072      // per-bucket record capacity in bucket_gather LDS

typedef __attribute__((ext_vector_type(8))) short bf16x8;
typedef __attribute__((ext_vector_type(4))) float f32x4;

// ---- bf16 helpers (RNE) ---------------------------------------------------
static __device__ __forceinline__ unsigned short f2bf(float f) {
  unsigned int u = __float_as_uint(f);
  u += 0x7FFFu + ((u >> 16) & 1u);
  return (unsigned short)(u >> 16);
}
static __device__ __forceinline__ float bf2f(unsigned short s) {
  return __uint_as_float((unsigned int)s << 16);
}

// ---------------------------------------------------------------------------
// pack weights into bf16 MFMA B-fragments. 18 mats:
//   0..7 = W1 rels, 8 = root1, 9..16 = W2 rels, 17 = root2
// ---------------------------------------------------------------------------
__global__ __launch_bounds__(512) void pack_wfrag(
    const float* __restrict__ W1, const float* __restrict__ rt1,
    const float* __restrict__ W2, const float* __restrict__ rt2,
    bf16x8* __restrict__ frag)
{
  const int mat = blockIdx.x;    // 0..17
  const float* W = (mat < 8)  ? (W1 + (size_t)mat * 4096)
                 : (mat == 8) ? rt1
                 : (mat < 17) ? (W2 + (size_t)(mat - 9) * 4096)
                              : rt2;
  const int idx = threadIdx.x;   // 0..511
  const int nt = idx >> 7;
  const int ks = (idx >> 6) & 1;
  const int l  = idx & 63;
  const int col = nt * 16 + (l & 15);
  const int k0  = ks * 32 + (l >> 4) * 8;
  bf16x8 f;
#pragma unroll
  for (int j = 0; j < 8; ++j)
    f[j] = (short)f2bf(W[(size_t)(k0 + j) * 64 + col]);
  frag[(((size_t)mat * 4 + nt) * 2 + ks) * 64 + l] = f;
}

// ---------------------------------------------------------------------------
// Fused MFMA transform: r<8 -> hb[r] = bf16(x@W[r]); r==8 -> out = x@root + b
// ---------------------------------------------------------------------------
__global__ __launch_bounds__(256) void mfma_transform(
    const float* __restrict__ x,
    const bf16x8* __restrict__ wfrag,        // [9][4][2][64] layer base
    const float* __restrict__ bias,
    unsigned short* __restrict__ hb,
    float* __restrict__ out,
    int N)
{
  const int tid = threadIdx.x;
  const int l  = tid & 63;
  const int w  = tid >> 6;
  const int n0 = blockIdx.x * 128 + w * 32;
  const int lr = l & 15;
  const int lg = l >> 4;

  bf16x8 a[2][2];
#pragma unroll
  for (int mt = 0; mt < 2; ++mt) {
    const int row = n0 + mt * 16 + lr;
#pragma unroll
    for (int ks = 0; ks < 2; ++ks) {
      if (row < N) {
        const float* xp = &x[(size_t)row * 64 + ks * 32 + lg * 8];
        float4 v0 = *(const float4*)xp;
        float4 v1 = *(const float4*)(xp + 4);
        bf16x8 t;
        t[0] = (short)f2bf(v0.x); t[1] = (short)f2bf(v0.y);
        t[2] = (short)f2bf(v0.z); t[3] = (short)f2bf(v0.w);
        t[4] = (short)f2bf(v1.x); t[5] = (short)f2bf(v1.y);
        t[6] = (short)f2bf(v1.z); t[7] = (short)f2bf(v1.w);
        a[mt][ks] = t;
      } else {
        a[mt][ks] = (bf16x8)(short)0;
      }
    }
  }

  float bb[4];
#pragma unroll
  for (int nt = 0; nt < 4; ++nt) bb[nt] = bias[nt * 16 + lr];

  for (int r = 0; r < 9; ++r) {
    const bf16x8* wf = wfrag + (size_t)r * 512;
    bf16x8 b[4][2];
#pragma unroll
    for (int nt = 0; nt < 4; ++nt)
#pragma unroll
      for (int ks = 0; ks < 2; ++ks)
        b[nt][ks] = wf[(nt * 2 + ks) * 64 + l];

    f32x4 acc[2][4];
#pragma unroll
    for (int mt = 0; mt < 2; ++mt)
#pragma unroll
      for (int nt = 0; nt < 4; ++nt)
        acc[mt][nt] = (f32x4)(0.f);

#pragma unroll
    for (int ks = 0; ks < 2; ++ks)
#pragma unroll
      for (int mt = 0; mt < 2; ++mt)
#pragma unroll
        for (int nt = 0; nt < 4; ++nt)
          acc[mt][nt] = __builtin_amdgcn_mfma_f32_16x16x32_bf16(
              a[mt][ks], b[nt][ks], acc[mt][nt], 0, 0, 0);

    if (r < 8) {
      unsigned short* hr = hb + (size_t)r * N * 64;
#pragma unroll
      for (int mt = 0; mt < 2; ++mt) {
#pragma unroll
        for (int i = 0; i < 4; ++i) {
          const int node = n0 + mt * 16 + lg * 4 + i;
          if (node < N) {
            unsigned short* o = hr + (size_t)node * 64 + lr;
#pragma unroll
            for (int nt = 0; nt < 4; ++nt)
              o[nt * 16] = f2bf(acc[mt][nt][i]);
          }
        }
      }
    } else {
#pragma unroll
      for (int mt = 0; mt < 2; ++mt) {
#pragma unroll
        for (int i = 0; i < 4; ++i) {
          const int node = n0 + mt * 16 + lg * 4 + i;
          if (node < N) {
            float* o = out + (size_t)node * 64 + lr;
#pragma unroll
            for (int nt = 0; nt < 4; ++nt)
              o[nt * 16] = acc[mt][nt][i] + bb[nt];
          }
        }
      }
    }
  }
}

// ---------------------------------------------------------------------------
// CSR-lite build (one-pass scatter via saved per-block reservations):
//   zero -> bucket_count (hist + atomic-reserve, stores relof row)
//        -> scan_buckets (bcnt -> boff)
//        -> bin_scatter  (single pass, LDS cursors = boff + relof)
// record (u32): rel[3] << 24 | src[17] << 7 | local_dst[6]
// ---------------------------------------------------------------------------
__global__ __launch_bounds__(256) void zero_ints(int* __restrict__ p, int n)
{
  int i = blockIdx.x * 256 + threadIdx.x;
  if (i < n) p[i] = 0;
}

__global__ __launch_bounds__(256) void bucket_count(
    const int* __restrict__ dst, int* __restrict__ bcnt,
    int* __restrict__ relof, int E, int NB)
{
  __shared__ int lh[NBMAX];
  const int t = threadIdx.x;
  for (int i = t; i < NB; i += 256) lh[i] = 0;
  __syncthreads();
  const int base = blockIdx.x * EPB;
  const int cnt = min(EPB, E - base);
  for (int k = t; k < cnt; k += 256)
    atomicAdd(&lh[dst[base + k] >> DPB_SHIFT], 1);
  __syncthreads();
  int* rrow = relof + (size_t)blockIdx.x * NB;
  for (int i = t; i < NB; i += 256) {
    int c = lh[i];
    rrow[i] = c ? atomicAdd(&bcnt[i], c) : 0;
  }
}

__global__ __launch_bounds__(1024) void scan_buckets(
    const int* __restrict__ bcnt, int* __restrict__ boff, int NB, int E)
{
  __shared__ int sc[1024];
  const int t = threadIdx.x;
  int v = (t < NB) ? bcnt[t] : 0;
  sc[t] = v;
  __syncthreads();
  for (int off = 1; off < 1024; off <<= 1) {
    int u = (t >= off) ? sc[t - off] : 0;
    __syncthreads();
    sc[t] += u;
    __syncthreads();
  }
  if (t < NB) boff[t] = sc[t] - v;
  if (t == 0) boff[NB] = E;
}

__global__ __launch_bounds__(256) void bin_scatter(
    const int* __restrict__ src, const int* __restrict__ dst,
    const int* __restrict__ et,
    const int* __restrict__ boff, const int* __restrict__ relof,
    unsigned int* __restrict__ binned, int E, int NB)
{
  __shared__ int cur[NBMAX];
  const int t = threadIdx.x;
  const int* rrow = relof + (size_t)blockIdx.x * NB;
  for (int i = t; i < NB; i += 256) cur[i] = boff[i] + rrow[i];
  __syncthreads();
  const int base = blockIdx.x * EPB;
  const int cnt = min(EPB, E - base);
  for (int k = t; k < cnt; k += 256) {
    int e = base + k;
    int d = dst[e];
    int pos = atomicAdd(&cur[d >> DPB_SHIFT], 1);
    binned[pos] = ((unsigned)et[e] << 24) | ((unsigned)src[e] << 7) |
                  ((unsigned)d & (DPB - 1));
  }
}

// ---------------------------------------------------------------------------
// bucket_gather: one block per 64-dst bucket. LDS-sorts the bucket's records
// by local dst (hist + scan + scatter), then 64 nodes x 8 lanes gather with
// register accumulation (4-unrolled 16B h loads). Fuses old fill_bucket+gather.
// ---------------------------------------------------------------------------
static __device__ __forceinline__ void gadd(
    float* __restrict__ acc, const uint4& u)
{
  acc[0] += bf2f((unsigned short)u.x);
  acc[1] += bf2f((unsigned short)(u.x >> 16));
  acc[2] += bf2f((unsigned short)u.y);
  acc[3] += bf2f((unsigned short)(u.y >> 16));
  acc[4] += bf2f((unsigned short)u.z);
  acc[5] += bf2f((unsigned short)(u.z >> 16));
  acc[6] += bf2f((unsigned short)u.w);
  acc[7] += bf2f((unsigned short)(u.w >> 16));
}

__global__ __launch_bounds__(512) void bucket_gather(
    const unsigned int* __restrict__ binned,
    const int* __restrict__ boff,
    const unsigned short* __restrict__ hb,   // [8][N][64] bf16
    float* __restrict__ out,                 // [N][64] fp32 (holds x@root+b)
    int N, int do_relu)
{
  __shared__ unsigned int srt[BCAP];
  __shared__ int h[DPB], sc[DPB], cur[DPB];
  const int t = threadIdx.x;
  const int b = blockIdx.x;
  const int beg = boff[b], end = boff[b + 1];
  const int m = min(end - beg, BCAP);      // records sorted in LDS

  if (t < DPB) h[t] = 0;
  __syncthreads();
  for (int k = t; k < m; k += 512)
    atomicAdd(&h[binned[beg + k] & (DPB - 1)], 1);
  __syncthreads();
  if (t < DPB) sc[t] = h[t];
  __syncthreads();
  for (int off = 1; off < DPB; off <<= 1) {
    int u = (t < DPB && t >= off) ? sc[t - off] : 0;
    __syncthreads();
    if (t < DPB) sc[t] += u;
    __syncthreads();
  }
  if (t < DPB) cur[t] = sc[t] - h[t];
  __syncthreads();
  for (int k = t; k < m; k += 512) {
    unsigned int r = binned[beg + k];
    int pos = atomicAdd(&cur[r & (DPB - 1)], 1);
    srt[pos] = r;
  }
  __syncthreads();

  const int nl = t >> 3;                   // 0..63 local node
  const int node = (b << DPB_SHIFT) + nl;
  const int l8 = (t & 7) * 8;

  float acc[8];
#pragma unroll
  for (int i = 0; i < 8; ++i) acc[i] = 0.f;

  if (node < N) {
    int p = sc[nl] - h[nl];
    const int pe = sc[nl];
    for (; p + 3 < pe; p += 4) {
      unsigned w0 = srt[p],     w1 = srt[p + 1];
      unsigned w2 = srt[p + 2], w3 = srt[p + 3];
      uint4 u0 = *(const uint4*)&hb[(((size_t)(w0 >> 24) * N + ((w0 >> 7) & 0x1FFFFu)) << 6) + l8];
      uint4 u1 = *(const uint4*)&hb[(((size_t)(w1 >> 24) * N + ((w1 >> 7) & 0x1FFFFu)) << 6) + l8];
      uint4 u2 = *(const uint4*)&hb[(((size_t)(w2 >> 24) * N + ((w2 >> 7) & 0x1FFFFu)) << 6) + l8];
      uint4 u3 = *(const uint4*)&hb[(((size_t)(w3 >> 24) * N + ((w3 >> 7) & 0x1FFFFu)) << 6) + l8];
      gadd(acc, u0); gadd(acc, u1); gadd(acc, u2); gadd(acc, u3);
    }
    for (; p < pe; ++p) {
      unsigned w0 = srt[p];
      uint4 u0 = *(const uint4*)&hb[(((size_t)(w0 >> 24) * N + ((w0 >> 7) & 0x1FFFFu)) << 6) + l8];
      gadd(acc, u0);
    }
    // overflow records (bucket bigger than BCAP): slow path, ~never taken
    for (int k = BCAP; k < end - beg; ++k) {
      unsigned w0 = binned[beg + k];
      if ((int)(w0 & (DPB - 1)) == nl) {
        uint4 u0 = *(const uint4*)&hb[(((size_t)(w0 >> 24) * N + ((w0 >> 7) & 0x1FFFFu)) << 6) + l8];
        gadd(acc, u0);
      }
    }

    float* o = out + ((size_t)node << 6) + l8;
    float4 c0 = *(float4*)o;
    float4 c1 = *(float4*)(o + 4);
    c0.x += acc[0]; c0.y += acc[1]; c0.z += acc[2]; c0.w += acc[3];
    c1.x += acc[4]; c1.y += acc[5]; c1.z += acc[6]; c1.w += acc[7];
    if (do_relu) {
      c0.x = fmaxf(c0.x, 0.f); c0.y = fmaxf(c0.y, 0.f);
      c0.z = fmaxf(c0.z, 0.f); c0.w = fmaxf(c0.w, 0.f);
      c1.x = fmaxf(c1.x, 0.f); c1.y = fmaxf(c1.y, 0.f);
      c1.z = fmaxf(c1.z, 0.f); c1.w = fmaxf(c1.w, 0.f);
    }
    *(float4*)o = c0;
    *(float4*)(o + 4) = c1;
  }
}

// ---------------------------------------------------------------------------
// FALLBACK path kernels (ws too small): fp32 vector transform + atomic scatter
// ---------------------------------------------------------------------------
__global__ __launch_bounds__(128) void rgcn_transform(
    const float* __restrict__ x,
    const float* __restrict__ Wc,
    unsigned short* __restrict__ hb,
    int N)
{
  const int r = blockIdx.y;
  const float* W = Wc + (size_t)r * DF * DF;

  __shared__ float Ws[DF * DF];
  __shared__ float Xs[128 * 65];

  const int tid = threadIdx.x;
  const int n0 = blockIdx.x * 128;
  const int nrem = N - n0;

  {
    const float4* Wv = (const float4*)W;
    float4* Wsv = (float4*)Ws;
#pragma unroll
    for (int j = 0; j < 8; ++j) Wsv[tid + j * 128] = Wv[tid + j * 128];
  }
#pragma unroll
  for (int j = 0; j < 16; ++j) {
    int idx = tid + j * 128;
    int n = idx >> 4;
    int c4 = (idx & 15) * 4;
    float4 v = make_float4(0.f, 0.f, 0.f, 0.f);
    if (n < nrem) v = *(const float4*)&x[(size_t)(n0 + n) * DF + c4];
    float* p = &Xs[n * 65 + c4];
    p[0] = v.x; p[1] = v.y; p[2] = v.z; p[3] = v.w;
  }
  __syncthreads();

  const int fg = (tid & 7) * 8;
  const int ng = (tid >> 3) * 8;

  float4 a0[8], a1[8];
#pragma unroll
  for (int i = 0; i < 8; ++i) {
    a0[i] = make_float4(0.f, 0.f, 0.f, 0.f);
    a1[i] = make_float4(0.f, 0.f, 0.f, 0.f);
  }

#pragma unroll 4
  for (int d = 0; d < DF; ++d) {
    float4 w0 = *(const float4*)&Ws[d * DF + fg];
    float4 w1 = *(const float4*)&Ws[d * DF + fg + 4];
#pragma unroll
    for (int i = 0; i < 8; ++i) {
      float xv = Xs[(ng + i) * 65 + d];
      a0[i].x += xv * w0.x; a0[i].y += xv * w0.y;
      a0[i].z += xv * w0.z; a0[i].w += xv * w0.w;
      a1[i].x += xv * w1.x; a1[i].y += xv * w1.y;
      a1[i].z += xv * w1.z; a1[i].w += xv * w1.w;
    }
  }

#pragma unroll
  for (int i = 0; i < 8; ++i) {
    int n = ng + i;
    if (n < nrem) {
      uint4 pk;
      pk.x = (unsigned)f2bf(a0[i].x) | ((unsigned)f2bf(a0[i].y) << 16);
      pk.y = (unsigned)f2bf(a0[i].z) | ((unsigned)f2bf(a0[i].w) << 16);
      pk.z = (unsigned)f2bf(a1[i].x) | ((unsigned)f2bf(a1[i].y) << 16);
      pk.w = (unsigned)f2bf(a1[i].z) | ((unsigned)f2bf(a1[i].w) << 16);
      unsigned short* op = hb + (((size_t)r * N + (n0 + n)) << 6) + fg;
      *(uint4*)op = pk;
    }
  }
}

__global__ __launch_bounds__(128) void rgcn_root_epilogue(
    const float* __restrict__ x,
    const float* __restrict__ root,
    const float* __restrict__ bias,
    float* __restrict__ out,
    int N, int mode)
{
  __shared__ float Ws[DF * DF];
  __shared__ float Xs[128 * 65];

  const int tid = threadIdx.x;
  const int n0 = blockIdx.x * 128;
  const int nrem = N - n0;

  {
    const float4* Wv = (const float4*)root;
    float4* Wsv = (float4*)Ws;
#pragma unroll
    for (int j = 0; j < 8; ++j) Wsv[tid + j * 128] = Wv[tid + j * 128];
  }
#pragma unroll
  for (int j = 0; j < 16; ++j) {
    int idx = tid + j * 128;
    int n = idx >> 4;
    int c4 = (idx & 15) * 4;
    float4 v = make_float4(0.f, 0.f, 0.f, 0.f);
    if (n < nrem) v = *(const float4*)&x[(size_t)(n0 + n) * DF + c4];
    float* p = &Xs[n * 65 + c4];
    p[0] = v.x; p[1] = v.y; p[2] = v.z; p[3] = v.w;
  }
  __syncthreads();

  const int fg = (tid & 7) * 8;
  const int ng = (tid >> 3) * 8;

  float4 a0[8], a1[8];
#pragma unroll
  for (int i = 0; i < 8; ++i) {
    a0[i] = make_float4(0.f, 0.f, 0.f, 0.f);
    a1[i] = make_float4(0.f, 0.f, 0.f, 0.f);
  }

#pragma unroll 4
  for (int d = 0; d < DF; ++d) {
    float4 w0 = *(const float4*)&Ws[d * DF + fg];
    float4 w1 = *(const float4*)&Ws[d * DF + fg + 4];
#pragma unroll
    for (int i = 0; i < 8; ++i) {
      float xv = Xs[(ng + i) * 65 + d];
      a0[i].x += xv * w0.x; a0[i].y += xv * w0.y;
      a0[i].z += xv * w0.z; a0[i].w += xv * w0.w;
      a1[i].x += xv * w1.x; a1[i].y += xv * w1.y;
      a1[i].z += xv * w1.z; a1[i].w += xv * w1.w;
    }
  }

  float4 bb0 = *(const float4*)&bias[fg];
  float4 bb1 = *(const float4*)&bias[fg + 4];

#pragma unroll
  for (int i = 0; i < 8; ++i) {
    int n = ng + i;
    if (n < nrem) {
      float* op = out + (size_t)(n0 + n) * DF + fg;
      float4 o0 = *(float4*)op;
      float4 o1 = *(float4*)(op + 4);
      o0.x += a0[i].x + bb0.x; o0.y += a0[i].y + bb0.y;
      o0.z += a0[i].z + bb0.z; o0.w += a0[i].w + bb0.w;
      o1.x += a1[i].x + bb1.x; o1.y += a1[i].y + bb1.y;
      o1.z += a1[i].z + bb1.z; o1.w += a1[i].w + bb1.w;
      if (mode == 1) {
        o0.x = fmaxf(o0.x, 0.f); o0.y = fmaxf(o0.y, 0.f);
        o0.z = fmaxf(o0.z, 0.f); o0.w = fmaxf(o0.w, 0.f);
        o1.x = fmaxf(o1.x, 0.f); o1.y = fmaxf(o1.y, 0.f);
        o1.z = fmaxf(o1.z, 0.f); o1.w = fmaxf(o1.w, 0.f);
      }
      *(float4*)op = o0;
      *(float4*)(op + 4) = o1;
    }
  }
}

__global__ __launch_bounds__(256) void rgcn_scatter(
    const int* __restrict__ src, const int* __restrict__ dst,
    const int* __restrict__ et,
    const unsigned short* __restrict__ hb,
    float* __restrict__ out,
    int E, int N, int r0, int r1)
{
  long long g = (long long)blockIdx.x * 256 + threadIdx.x;
  int e = (int)(g >> 4);
  if (e >= E) return;
  int r = et[e];
  if (r < r0 || r >= r1) return;
  int f4 = ((int)g & 15) * 4;
  int s = src[e];
  int d = dst[e];
  ushort4 u = *(const ushort4*)&hb[(((size_t)(r - r0) * N + s) << 6) + f4];
  float* o = out + ((size_t)d << 6) + f4;
  atomicAdd(o + 0, bf2f(u.x));
  atomicAdd(o + 1, bf2f(u.y));
  atomicAdd(o + 2, bf2f(u.z));
  atomicAdd(o + 3, bf2f(u.w));
}

// ---------------------------------------------------------------------------
extern "C" void kernel_launch(void* const* d_in, const int* in_sizes, int n_in,
                              void* d_out, int out_size, void* d_ws, size_t ws_size,
                              hipStream_t stream) {
  const int* adj    = (const int*)d_in[0];    // [2, E]
  const float* feat = (const float*)d_in[1];  // [N, 64]
  const int* et     = (const int*)d_in[2];    // [E]
  const float* W1   = (const float*)d_in[3];
  const float* rt1  = (const float*)d_in[4];
  const float* b1   = (const float*)d_in[5];
  const float* W2   = (const float*)d_in[6];
  const float* rt2  = (const float*)d_in[7];
  const float* b2   = (const float*)d_in[8];

  const int E = in_sizes[0] / 2;
  const int N = in_sizes[1] / DF;
  const int* srcp = adj;
  const int* dstp = adj + E;

  float* out = (float*)d_out;
  const size_t ND = (size_t)N * DF;
  const int nblk = (N + 127) / 128;
  const int NB = (N + DPB - 1) >> DPB_SHIFT;
  const int ebk = (E + EPB - 1) / EPB;

  // ws layout: hb bf16[8,N,64] | wfrag[18*512 bf16x8] | binned u32[E] |
  //            relof int[ebk*NB] | bcnt[NB] | boff[NB+1]
  const size_t wfrag_elems = (size_t)18 * 512;
  const size_t need_csr = 8 * ND * 2 + wfrag_elems * 16 +
                          (size_t)E * 4 + (size_t)ebk * NB * 4 +
                          ((size_t)2 * NB + 1) * 4;

  if (ws_size >= need_csr && NB <= NBMAX && N < (1 << 17)) {
    unsigned short* hb = (unsigned short*)d_ws;
    bf16x8* wfrag = (bf16x8*)(hb + 8 * ND);
    unsigned int* binned = (unsigned int*)(wfrag + wfrag_elems);
    int* relof = (int*)(binned + E);
    int* bcnt = relof + (size_t)ebk * NB;
    int* boff = bcnt + NB;

    // ---- pack weights (independent) ----
    pack_wfrag<<<18, 512, 0, stream>>>(W1, rt1, W2, rt2, wfrag);

    // ---- build bucket-grouped edge list once (same graph both layers) ----
    zero_ints<<<(NB + 255) / 256, 256, 0, stream>>>(bcnt, NB);
    bucket_count<<<ebk, 256, 0, stream>>>(dstp, bcnt, relof, E, NB);
    scan_buckets<<<1, 1024, 0, stream>>>(bcnt, boff, NB, E);
    bin_scatter<<<ebk, 256, 0, stream>>>(srcp, dstp, et, boff, relof,
                                         binned, E, NB);

    // ---- layer 1: out = relu( agg(h1) + feat@rt1 + b1 ) ----
    mfma_transform<<<nblk, 256, 0, stream>>>(feat, wfrag, b1, hb, out, N);
    bucket_gather<<<NB, 512, 0, stream>>>(binned, boff, hb, out, N, 1);

    // ---- layer 2: out = agg(h2) + out@rt2 + b2 ----
    mfma_transform<<<nblk, 256, 0, stream>>>(out, wfrag + (size_t)9 * 512,
                                             b2, hb, out, N);
    bucket_gather<<<NB, 512, 0, stream>>>(binned, boff, hb, out, N, 0);
    return;
  }

  // ---------------- fallback: atomic scatter ----------------
  size_t per_rel = ND * sizeof(unsigned short);
  size_t xmid_b = ND * sizeof(float);
  int RC = 1;
  if (ws_size > per_rel + xmid_b) {
    size_t rc = (ws_size - xmid_b) / per_rel;
    RC = rc >= NREL ? NREL : (int)rc;
  }
  unsigned short* hb = (unsigned short*)d_ws;
  float* xmid = (float*)((char*)d_ws + (size_t)RC * per_rel);
  const int sblk = (int)(((size_t)E * 16 + 255) / 256);

  for (int layer = 0; layer < 2; ++layer) {
    const float* xin = layer ? xmid : feat;
    const float* W   = layer ? W2 : W1;
    const float* rt  = layer ? rt2 : rt1;
    const float* bs  = layer ? b2 : b1;
    float* o         = layer ? out : xmid;

    hipMemsetAsync(o, 0, ND * sizeof(float), stream);
    for (int r0 = 0; r0 < NREL; r0 += RC) {
      int rc = (NREL - r0) < RC ? (NREL - r0) : RC;
      rgcn_transform<<<dim3(nblk, rc), 128, 0, stream>>>(
          xin, W + (size_t)r0 * DF * DF, hb, N);
      rgcn_scatter<<<sblk, 256, 0, stream>>>(
          srcp, dstp, et, hb, o, E, N, r0, r0 + rc);
    }
    rgcn_root_epilogue<<<nblk, 128, 0, stream>>>(xin, rt, bs, o, N,
                                                 layer == 0 ? 1 : 2);
  }
}